// Round 7
// baseline (590.839 us; speedup 1.0000x reference)
//
#include <hip/hip_runtime.h>

// 2-layer GCN, CSR-gather, bf16 payloads.
//   deg(global atomics) -> scan1/scan2/finalize -> [scatter ∥ gemm, 1:1]
//   -> gather1 -> gather2f (gather + W2 matmul + pooled output, fused).
// Kept: bf16 payloads (R10), fused final (R10), uint4 gathers (R13),
// K-split coalesced gemm loads (R16), 2 nodes/thread gemm (R17),
// 1:1 scatter/gemm block interleave for CU overlap (R9/R13).
// R18: the 5-kernel counting-sort pipeline (hist -> scan(305K) -> scatter
//   -> sort) replaced by direct global-atomic CSR build: deg via
//   atomicAdd (3.2M adds over 200K addrs ~= 16/addr, no hot-spot,
//   device-scope per m20), scan(200K)+finalize(offs/cursor/dinv), then
//   csr[atomicAdd(&cursor[c],1)] = row (within-node order is irrelevant
//   to the gather sums).  sort_kernel and the h1b intermediate die: gemm
//   applies dinv and writes h1p directly (one fp32 round instead of two).

#define TPB 256
#define CHUNK 4096          // edges per scatter block
#define W1S 20              // w1s k-row stride in floats (bank-spread pad)

__device__ __forceinline__ float bf2f(unsigned short u) {
    union { unsigned int i; float f; } v; v.i = ((unsigned int)u) << 16; return v.f;
}
__device__ __forceinline__ unsigned short f2bf(float f) {
    union { float f; unsigned int i; } v; v.f = f;
    unsigned int r = v.i + 0x7fff + ((v.i >> 16) & 1);   // RNE
    return (unsigned short)(r >> 16);
}
// accumulate 8 bf16 (one uint4) into a[0..7]; mask kills invalid edges
__device__ __forceinline__ void bfacc8(uint4 v, unsigned int m, float* a) {
    union { unsigned int i; float f; } lo, hi;
    v.x &= m; v.y &= m; v.z &= m; v.w &= m;
    lo.i = v.x << 16; hi.i = v.x & 0xffff0000u; a[0] += lo.f; a[1] += hi.f;
    lo.i = v.y << 16; hi.i = v.y & 0xffff0000u; a[2] += lo.f; a[3] += hi.f;
    lo.i = v.z << 16; hi.i = v.z & 0xffff0000u; a[4] += lo.f; a[5] += hi.f;
    lo.i = v.w << 16; hi.i = v.w & 0xffff0000u; a[6] += lo.f; a[7] += hi.f;
}
__device__ __forceinline__ void bfunp8(uint4 v, float* a) {
    union { unsigned int i; float f; } lo, hi;
    lo.i = v.x << 16; hi.i = v.x & 0xffff0000u; a[0] = lo.f; a[1] = hi.f;
    lo.i = v.y << 16; hi.i = v.y & 0xffff0000u; a[2] = lo.f; a[3] = hi.f;
    lo.i = v.z << 16; hi.i = v.z & 0xffff0000u; a[4] = lo.f; a[5] = hi.f;
    lo.i = v.w << 16; hi.i = v.w & 0xffff0000u; a[6] = lo.f; a[7] = hi.f;
}

// deg[c] = #edges with col==c.  Coalesced col read, fire-and-forget atomics.
__global__ __launch_bounds__(TPB) void deg_kernel(const int* __restrict__ col,
                                                  int* __restrict__ deg, int E) {
    int base = (int)blockIdx.x * (TPB * 8) + threadIdx.x;
#pragma unroll
    for (int k = 0; k < 8; ++k) {
        int e = base + k * TPB;
        if (e < E) atomicAdd(&deg[col[e]], 1);
    }
}

// scan1: per-256-block exclusive scan, bsum[b]=block total
__global__ __launch_bounds__(TPB) void scan1_kernel(const int* __restrict__ in,
                                                    int* __restrict__ out,
                                                    int* __restrict__ bsum, int L) {
    __shared__ int s[TPB];
    int t = threadIdx.x;
    int i = blockIdx.x * TPB + t;
    int d = (i < L) ? in[i] : 0;
    s[t] = d; __syncthreads();
    for (int off = 1; off < TPB; off <<= 1) {
        int v = (t >= off) ? s[t - off] : 0;
        __syncthreads();
        s[t] += v;
        __syncthreads();
    }
    if (i < L) out[i] = s[t] - d;
    if (t == TPB - 1) bsum[blockIdx.x] = s[t];
}

// scan2: single-block exclusive scan of up to 2048 block sums (2 elems/thread)
__global__ __launch_bounds__(1024) void scan2_kernel(int* __restrict__ bsum, int nb) {
    __shared__ int s[1024];
    int t = threadIdx.x;
    int i0 = t * 2, i1 = t * 2 + 1;
    int v0 = (i0 < nb) ? bsum[i0] : 0;
    int v1 = (i1 < nb) ? bsum[i1] : 0;
    int pv = v0 + v1;
    s[t] = pv; __syncthreads();
    for (int off = 1; off < 1024; off <<= 1) {
        int u = (t >= off) ? s[t - off] : 0;
        __syncthreads();
        s[t] += u;
        __syncthreads();
    }
    int exc = s[t] - pv;
    if (i0 < nb) bsum[i0] = exc;
    if (i1 < nb) bsum[i1] = exc + v0;
}

// finalize: offs = dscan + bsum add-back; cursor = offs; dinv = rsqrt(deg+1)
__global__ __launch_bounds__(TPB) void finalize_kernel(
        const int* __restrict__ deg, const int* __restrict__ dscan,
        const int* __restrict__ bsum,
        int* __restrict__ offs, int* __restrict__ cursor,
        float* __restrict__ dinv, int N, int E) {
    int n = blockIdx.x * TPB + threadIdx.x;
    if (n < N) {
        int o = dscan[n] + bsum[n >> 8];
        offs[n] = o;
        cursor[n] = o;
        dinv[n] = rsqrtf((float)deg[n] + 1.0f);
    }
    if (n == 0) offs[N] = E;
}

// [scatter ∥ gemm], block-interleaved 1:1 for CU overlap.
// Scatter: csr[atomicAdd(&cursor[col],1)] = row  (order within node free).
// Gemm: h1p[n] = bf16(dinv[n] * (x[n] @ W1)).  4 threads/node K-split,
//   2 nodes/thread (g, g+64): each W1 ds_read_b128 feeds 32 FMA; 16
//   coalesced x loads upfront (fixed i: 4 lanes = one 64B line);
//   butterfly reduce over 4 K-split lanes; lane q stores feats 4q..4q+3.
__global__ __launch_bounds__(TPB) void scatgemm_kernel(
        const int* __restrict__ row, const int* __restrict__ col,
        int* __restrict__ cursor, int* __restrict__ csr, int E,
        const float* __restrict__ x, const float* __restrict__ W1,
        const float* __restrict__ dinv,
        unsigned short* __restrict__ h1p, int N, int ns, int ng) {
    __shared__ float w1s[128 * W1S];
    int b = (int)blockIdx.x, t = threadIdx.x;
    int M = min(ns, ng);
    int role, id;
    if (b < 2 * M) { role = b & 1; id = b >> 1; }
    else           { role = (ns > ng) ? 0 : 1; id = b - M; }

    if (role == 0) {                         // atomic CSR scatter
        int e0 = id * CHUNK;
        int e1 = min(e0 + CHUNK, E);
        for (int e = e0 + t; e < e1; e += TPB) {
            int c = col[e];
            int pos = atomicAdd(&cursor[c], 1);    // global atomic, L2
            csr[pos] = row[e];
        }
        return;
    }
    // gemm role
    for (int i = t; i < 128 * 16; i += TPB)
        w1s[(i >> 4) * W1S + (i & 15)] = W1[i];
    __syncthreads();
    int g = t >> 2, q = t & 3;
    int nA = id * 128 + g;
    int nB = nA + 64;
    int nAc = min(nA, N - 1), nBc = min(nB, N - 1);
    const float4* xA = (const float4*)(x + (size_t)nAc * 128);
    const float4* xB = (const float4*)(x + (size_t)nBc * 128);
    float4 xvA[8], xvB[8];
#pragma unroll
    for (int i = 0; i < 8; ++i) xvA[i] = xA[i * 4 + q];   // 16 loads in flight
#pragma unroll
    for (int i = 0; i < 8; ++i) xvB[i] = xB[i * 4 + q];
    float accA[16], accB[16];
#pragma unroll
    for (int k = 0; k < 16; ++k) { accA[k] = 0.f; accB[k] = 0.f; }
#pragma unroll
    for (int i = 0; i < 8; ++i) {
        float xjA[4] = {xvA[i].x, xvA[i].y, xvA[i].z, xvA[i].w};
        float xjB[4] = {xvB[i].x, xvB[i].y, xvB[i].z, xvB[i].w};
#pragma unroll
        for (int j = 0; j < 4; ++j) {
            int k = i * 16 + q * 4 + j;
            const float4* w4 = (const float4*)&w1s[k * W1S];
            float4 wa = w4[0], wb = w4[1], wc = w4[2], wd = w4[3];
            float xa = xjA[j], xb = xjB[j];
            accA[0]  = fmaf(xa, wa.x, accA[0]);  accA[1]  = fmaf(xa, wa.y, accA[1]);
            accA[2]  = fmaf(xa, wa.z, accA[2]);  accA[3]  = fmaf(xa, wa.w, accA[3]);
            accA[4]  = fmaf(xa, wb.x, accA[4]);  accA[5]  = fmaf(xa, wb.y, accA[5]);
            accA[6]  = fmaf(xa, wb.z, accA[6]);  accA[7]  = fmaf(xa, wb.w, accA[7]);
            accA[8]  = fmaf(xa, wc.x, accA[8]);  accA[9]  = fmaf(xa, wc.y, accA[9]);
            accA[10] = fmaf(xa, wc.z, accA[10]); accA[11] = fmaf(xa, wc.w, accA[11]);
            accA[12] = fmaf(xa, wd.x, accA[12]); accA[13] = fmaf(xa, wd.y, accA[13]);
            accA[14] = fmaf(xa, wd.z, accA[14]); accA[15] = fmaf(xa, wd.w, accA[15]);
            accB[0]  = fmaf(xb, wa.x, accB[0]);  accB[1]  = fmaf(xb, wa.y, accB[1]);
            accB[2]  = fmaf(xb, wa.z, accB[2]);  accB[3]  = fmaf(xb, wa.w, accB[3]);
            accB[4]  = fmaf(xb, wb.x, accB[4]);  accB[5]  = fmaf(xb, wb.y, accB[5]);
            accB[6]  = fmaf(xb, wb.z, accB[6]);  accB[7]  = fmaf(xb, wb.w, accB[7]);
            accB[8]  = fmaf(xb, wc.x, accB[8]);  accB[9]  = fmaf(xb, wc.y, accB[9]);
            accB[10] = fmaf(xb, wc.z, accB[10]); accB[11] = fmaf(xb, wc.w, accB[11]);
            accB[12] = fmaf(xb, wd.x, accB[12]); accB[13] = fmaf(xb, wd.y, accB[13]);
            accB[14] = fmaf(xb, wd.z, accB[14]); accB[15] = fmaf(xb, wd.w, accB[15]);
        }
    }
    // butterfly-reduce both accs across the 4 K-split lanes
#pragma unroll
    for (int d = 1; d < 4; d <<= 1) {
#pragma unroll
        for (int k = 0; k < 16; ++k) {
            accA[k] += __shfl_xor(accA[k], d, 4);
            accB[k] += __shfl_xor(accB[k], d, 4);
        }
    }
    if (nA < N) {                            // lane q stores feats 4q..4q+3
        float dA = dinv[nA];
        unsigned int u0 = (unsigned int)f2bf(dA * accA[4 * q]) |
                          ((unsigned int)f2bf(dA * accA[4 * q + 1]) << 16);
        unsigned int u1 = (unsigned int)f2bf(dA * accA[4 * q + 2]) |
                          ((unsigned int)f2bf(dA * accA[4 * q + 3]) << 16);
        *(uint2*)&h1p[(size_t)nA * 16 + 4 * q] = make_uint2(u0, u1);
    }
    if (nB < N) {
        float dB = dinv[nB];
        unsigned int u0 = (unsigned int)f2bf(dB * accB[4 * q]) |
                          ((unsigned int)f2bf(dB * accB[4 * q + 1]) << 16);
        unsigned int u1 = (unsigned int)f2bf(dB * accB[4 * q + 2]) |
                          ((unsigned int)f2bf(dB * accB[4 * q + 3]) << 16);
        *(uint2*)&h1p[(size_t)nB * 16 + 4 * q] = make_uint2(u0, u1);
    }
}

// gather1: 16 lanes/node, uint4 gathers: lane l -> edge slot (l>>1), half-row
// (l&1).  Per 16-edge csr window: 2 gather instrs (16 lanes x 16B) cover
// 16 edges x full row.  8-lane tree reduce; lanes 0/1 finalize 8 feats each.
// h2p[c] = bf16( dinv[c]*relu( dinv[c]*(sum h1p[src] + h1p[c]) + b1 ) )
__global__ __launch_bounds__(TPB) void gather1_kernel(const int* __restrict__ csr,
                                                      const int* __restrict__ offs,
                                                      const unsigned short* __restrict__ h1p,
                                                      const float* __restrict__ dinv,
                                                      const float* __restrict__ b1,
                                                      unsigned short* __restrict__ h2p, int N) {
    int t = threadIdx.x;
    int c = blockIdx.x * 16 + (t >> 4);
    int l = t & 15;
    int half = l & 1;                        // which 8-feature half-row
    int sub  = l >> 1;                       // edge slot 0..7
    if (c >= N) return;
    int p0 = offs[c], p1 = offs[c + 1];
    float a[8];
#pragma unroll
    for (int k = 0; k < 8; ++k) a[k] = 0.f;
    for (int p = p0; p < p1; p += 16) {
        int s16 = csr[min(p + l, p1 - 1)];
#pragma unroll
        for (int h = 0; h < 2; ++h) {
            int e = 8 * h + sub;
            int src = __shfl(s16, e, 16);
            unsigned int m = ((p + e) < p1) ? 0xffffffffu : 0u;
            uint4 v = *(const uint4*)&h1p[(size_t)src * 16 + 8 * half];
            bfacc8(v, m, a);
        }
    }
#pragma unroll
    for (int d = 2; d < 16; d <<= 1) {
#pragma unroll
        for (int k = 0; k < 8; ++k) a[k] += __shfl_xor(a[k], d, 16);
    }
    if (l < 2) {                             // l==half here
        float dc = dinv[c];
        uint4 sv = *(const uint4*)&h1p[(size_t)c * 16 + 8 * l];
        float sf[8];
        bfunp8(sv, sf);
        unsigned int uo[4];
#pragma unroll
        for (int q = 0; q < 4; ++q) {
            float r0 = fmaf(dc, a[2 * q] + sf[2 * q], b1[8 * l + 2 * q]);
            float r1 = fmaf(dc, a[2 * q + 1] + sf[2 * q + 1], b1[8 * l + 2 * q + 1]);
            r0 = dc * fmaxf(r0, 0.f);
            r1 = dc * fmaxf(r1, 0.f);
            uo[q] = (unsigned int)f2bf(r0) | ((unsigned int)f2bf(r1) << 16);
        }
        *(uint4*)&h2p[(size_t)c * 16 + 8 * l] = make_uint4(uo[0], uo[1], uo[2], uo[3]);
    }
}

// gather2f: fused gather2 + W2 matmul + sorted-batch pooling.  Block = 64 nodes.
// Phase 1: 16 groups x 16 lanes gather a2 rows (4 nodes/group, uint4 gathers
// as in gather1) into LDS asT.
// Phase 2: wave w: 64 lanes = output dims, 16 nodes from asT, W2 slice in regs,
//          run-accumulate; uniform-batch blocks pool in LDS, flush 64 atomics.
__global__ __launch_bounds__(TPB) void gather2f_kernel(
        const int* __restrict__ csr, const int* __restrict__ offs,
        const unsigned short* __restrict__ h2p, const float* __restrict__ dinv,
        const float* __restrict__ W2, const float* __restrict__ b2,
        const int* __restrict__ batch, float* __restrict__ out, int N) {
    __shared__ float w2s[16 * 64];
    __shared__ float asT[64 * 17];
    __shared__ float pool[64];
    int t = threadIdx.x;
    for (int i = t; i < 16 * 64; i += TPB) w2s[i] = W2[i];
    if (t < 64) pool[t] = 0.f;

    int n0 = blockIdx.x * 64;
    int nLast = min(n0 + 63, N - 1);
    int g0 = batch[n0];
    bool uniform = (batch[nLast] == g0);     // batch sorted

    // phase 1: gather (4 nodes per 16-lane group, uint4 loads)
    int grp = t >> 4, l = t & 15;
    int half = l & 1, sub = l >> 1;
#pragma unroll 1
    for (int it = 0; it < 4; ++it) {
        int m = grp * 4 + it;
        int c = n0 + m;
        if (c < N) {
            int p0 = offs[c], p1 = offs[c + 1];
            float a[8];
#pragma unroll
            for (int k = 0; k < 8; ++k) a[k] = 0.f;
            for (int p = p0; p < p1; p += 16) {
                int s16 = csr[min(p + l, p1 - 1)];
#pragma unroll
                for (int h = 0; h < 2; ++h) {
                    int e = 8 * h + sub;
                    int src = __shfl(s16, e, 16);
                    unsigned int mm = ((p + e) < p1) ? 0xffffffffu : 0u;
                    uint4 v = *(const uint4*)&h2p[(size_t)src * 16 + 8 * half];
                    bfacc8(v, mm, a);
                }
            }
#pragma unroll
            for (int d = 2; d < 16; d <<= 1) {
#pragma unroll
                for (int k = 0; k < 8; ++k) a[k] += __shfl_xor(a[k], d, 16);
            }
            if (l < 2) {
                float dc = dinv[c];
                uint4 sv = *(const uint4*)&h2p[(size_t)c * 16 + 8 * l];
                float sf[8];
                bfunp8(sv, sf);
#pragma unroll
                for (int k = 0; k < 8; ++k)
                    asT[m * 17 + 8 * l + k] = dc * (a[k] + sf[k]);
            }
        }
    }
    __syncthreads();

    // phase 2: wave w covers nodes n0+16w .. n0+16w+15
    int wave = t >> 6, j = t & 63;
    float w2reg[16];
#pragma unroll
    for (int kx = 0; kx < 16; ++kx) w2reg[kx] = w2s[kx * 64 + j];
    float b2j = b2[j];
    float val = 0.f;
    int g_cur = -1;
#pragma unroll 1
    for (int mi = 0; mi < 16; ++mi) {
        int m = wave * 16 + mi;
        int c = n0 + m;
        if (c >= N) break;
        const float* ar = &asT[m * 17];
        float y = b2j;
#pragma unroll
        for (int kx = 0; kx < 16; ++kx) y = fmaf(ar[kx], w2reg[kx], y);
        if (uniform) {
            val += y;
        } else {
            int g = batch[c];
            if (g != g_cur) {
                if (g_cur >= 0) atomicAdd(&out[(size_t)g_cur * 64 + j], val);
                val = 0.f;
                g_cur = g;
            }
            val += y;
        }
    }
    if (uniform) {
        atomicAdd(&pool[j], val);            // LDS, 4-way per address
        __syncthreads();
        if (t < 64) atomicAdd(&out[(size_t)g0 * 64 + t], pool[t]);
    } else {
        if (g_cur >= 0) atomicAdd(&out[(size_t)g_cur * 64 + j], val);
    }
}

static inline size_t align64(size_t v) { return (v + 63) & ~(size_t)63; }

extern "C" void kernel_launch(void* const* d_in, const int* in_sizes, int n_in,
                              void* d_out, int out_size, void* d_ws, size_t ws_size,
                              hipStream_t stream) {
    const float* x     = (const float*)d_in[0];
    const int*   ei    = (const int*)d_in[1];
    const int*   batch = (const int*)d_in[2];
    const float* W1    = (const float*)d_in[3];
    const float* b1    = (const float*)d_in[4];
    const float* W2    = (const float*)d_in[5];
    const float* b2    = (const float*)d_in[6];

    const int N = in_sizes[0] / 128;
    const int E = in_sizes[1] / 2;
    const int* row = ei;        // edge_index[0]
    const int* col = ei + E;    // edge_index[1]

    const int NS   = (E + CHUNK - 1) / CHUNK;        // 782 scatter blocks
    const int NG   = (N + 127) / 128;                // 1563 gemm blocks
    const int NBD  = (E + TPB * 8 - 1) / (TPB * 8);  // 1563 deg blocks
    const int NBN  = (N + TPB - 1) / TPB;            // 782 (scan1/finalize)

    char* p = (char*)d_ws;
    int*            deg    = (int*)p;            p += align64((size_t)N * 4);
    int*            dscan  = (int*)p;            p += align64((size_t)N * 4);
    int*            bsum   = (int*)p;            p += align64(2048 * 4);
    int*            cursor = (int*)p;            p += align64((size_t)N * 4);
    int*            csr    = (int*)p;            p += align64((size_t)E * 4);
    int*            offs   = (int*)p;            p += align64((size_t)(N + 1) * 4);
    float*          dinv   = (float*)p;          p += align64((size_t)N * 4);
    unsigned short* h1p    = (unsigned short*)p; p += align64((size_t)N * 16 * 2);
    unsigned short* h2p    = (unsigned short*)p; p += align64((size_t)N * 16 * 2);
    float*          out    = (float*)d_out;

    hipMemsetAsync(out, 0, (size_t)out_size * sizeof(float), stream);
    hipMemsetAsync(deg, 0, (size_t)N * 4, stream);

    deg_kernel<<<NBD, TPB, 0, stream>>>(col, deg, E);
    scan1_kernel<<<NBN, TPB, 0, stream>>>(deg, dscan, bsum, N);
    scan2_kernel<<<1, 1024, 0, stream>>>(bsum, NBN);
    finalize_kernel<<<NBN, TPB, 0, stream>>>(deg, dscan, bsum, offs, cursor,
                                             dinv, N, E);
    scatgemm_kernel<<<NS + NG, TPB, 0, stream>>>(row, col, cursor, csr, E,
                                                 x, W1, dinv, h1p, N, NS, NG);
    gather1_kernel<<<(N + 15) / 16, TPB, 0, stream>>>(csr, offs, h1p, dinv, b1, h2p, N);
    gather2f_kernel<<<(N + 63) / 64, TPB, 0, stream>>>(csr, offs, h2p, dinv,
                                                       W2, b2, batch, out, N);
}

// Round 8
// 340.436 us; speedup vs baseline: 1.7355x; 1.7355x over previous
//
#include <hip/hip_runtime.h>

// 2-layer GCN, CSR-gather, bf16 payloads, zero global atomics.
//   hist(512-node buckets) -> scan1/scan2 -> [scatter ∥ gemm, 1:1] -> sort
//   -> gather1 -> gather2f (gather + W2 matmul + pooled output, fused).
// Kept: 1:1 scatter/gemm interleave (R9), 512-node buckets, packed 1-int
// bucket entries, bf16 h1 (R10), scan3g folded into consumers (R10),
// final fused into gather2 (R10), sorted coalesced bucket writes (R12),
// scan-diff counts + shfl scan + LDS union (R13), uint4 gathers (R13),
// K-split coalesced gemm loads (R16).
// R18 history: global-atomic CSR build REFUTED — csr[pos]=row random 4B
//   stores re-created the write amplification R12 killed (WRITE 208MB,
//   scatgemm 239us).  Bucketed sort's value = write coalescing, not
//   atomic avoidance.  Reverted to the R16 pipeline.
// R19: gather1/gather2f predicated loads.  Clamp-and-mask wasted ~47% of
//   scattered uint4 requests (deg+1 ~= 17 vs 16-edge windows: 64 issued,
//   34 useful per node).  Tail loads now branch-skipped (bulk windows are
//   uniformly active -> no divergence); both loads per lane still issue
//   before first use, so ILP is unchanged.

#define TPB 256
#define CHUNK 4096          // edges per stage-1 block
#define BK_SHIFT 9
#define NPB 512             // nodes per bucket = 1 << BK_SHIFT
#define W1S 20              // w1s k-row stride in floats (bank-spread pad)

__device__ __forceinline__ float bf2f(unsigned short u) {
    union { unsigned int i; float f; } v; v.i = ((unsigned int)u) << 16; return v.f;
}
__device__ __forceinline__ unsigned short f2bf(float f) {
    union { float f; unsigned int i; } v; v.f = f;
    unsigned int r = v.i + 0x7fff + ((v.i >> 16) & 1);   // RNE
    return (unsigned short)(r >> 16);
}
// accumulate 8 bf16 (one uint4) into a[0..7]
__device__ __forceinline__ void bfacc8(uint4 v, float* a) {
    union { unsigned int i; float f; } lo, hi;
    lo.i = v.x << 16; hi.i = v.x & 0xffff0000u; a[0] += lo.f; a[1] += hi.f;
    lo.i = v.y << 16; hi.i = v.y & 0xffff0000u; a[2] += lo.f; a[3] += hi.f;
    lo.i = v.z << 16; hi.i = v.z & 0xffff0000u; a[4] += lo.f; a[5] += hi.f;
    lo.i = v.w << 16; hi.i = v.w & 0xffff0000u; a[6] += lo.f; a[7] += hi.f;
}
__device__ __forceinline__ void bfunp8(uint4 v, float* a) {
    union { unsigned int i; float f; } lo, hi;
    lo.i = v.x << 16; hi.i = v.x & 0xffff0000u; a[0] = lo.f; a[1] = hi.f;
    lo.i = v.y << 16; hi.i = v.y & 0xffff0000u; a[2] = lo.f; a[3] = hi.f;
    lo.i = v.z << 16; hi.i = v.z & 0xffff0000u; a[4] = lo.f; a[5] = hi.f;
    lo.i = v.w << 16; hi.i = v.w & 0xffff0000u; a[6] = lo.f; a[7] = hi.f;
}

// S1a: counts[bk*nblk + blk] = #edges in block blk with col>>9 == bk
__global__ __launch_bounds__(TPB) void hist_kernel(const int* __restrict__ col,
                                                   int* __restrict__ counts,
                                                   int E, int nblk, int nbuck) {
    __shared__ int hist[512];
    int t = threadIdx.x;
    for (int i = t; i < nbuck; i += TPB) hist[i] = 0;
    __syncthreads();
    int e0 = blockIdx.x * CHUNK;
    for (int i = t; i < CHUNK; i += TPB) {
        int e = e0 + i;
        if (e < E) atomicAdd(&hist[col[e] >> BK_SHIFT], 1);   // LDS atomic
    }
    __syncthreads();
    for (int i = t; i < nbuck; i += TPB) counts[i * nblk + blockIdx.x] = hist[i];
}

// scan1: per-256-block exclusive scan (counts in place), bsum[b]=block total
__global__ __launch_bounds__(TPB) void scan1_kernel(const int* __restrict__ in,
                                                    int* __restrict__ out,
                                                    int* __restrict__ bsum, int L) {
    __shared__ int s[TPB];
    int t = threadIdx.x;
    int i = blockIdx.x * TPB + t;
    int d = (i < L) ? in[i] : 0;
    s[t] = d; __syncthreads();
    for (int off = 1; off < TPB; off <<= 1) {
        int v = (t >= off) ? s[t - off] : 0;
        __syncthreads();
        s[t] += v;
        __syncthreads();
    }
    if (i < L) out[i] = s[t] - d;
    if (t == TPB - 1) bsum[blockIdx.x] = s[t];
}

// scan2: single-block exclusive scan of up to 2048 block sums (2 elems/thread)
__global__ __launch_bounds__(1024) void scan2_kernel(int* __restrict__ bsum, int nb) {
    __shared__ int s[1024];
    int t = threadIdx.x;
    int i0 = t * 2, i1 = t * 2 + 1;
    int v0 = (i0 < nb) ? bsum[i0] : 0;
    int v1 = (i1 < nb) ? bsum[i1] : 0;
    int pv = v0 + v1;
    s[t] = pv; __syncthreads();
    for (int off = 1; off < 1024; off <<= 1) {
        int u = (t >= off) ? s[t - off] : 0;
        __syncthreads();
        s[t] += u;
        __syncthreads();
    }
    int exc = s[t] - pv;
    if (i0 < nb) bsum[i0] = exc;
    if (i1 < nb) bsum[i1] = exc + v0;
}

// cbase[f] = counts[f] + bsum[f>>8]   (scan3g folded into consumers)
__device__ __forceinline__ int cbase_at(const int* counts, const int* bsum, int f) {
    return counts[f] + bsum[f >> 8];
}

// S1c ∥ gemm, block-interleaved 1:1.
// Scatter: counts from scan diffs, shfl-scan local offsets, LDS counting
//   sort, bucket-ordered coalesced writes.
// Gemm: 4 threads/node K-split, coalesced line loads, no barriers (R16).
__global__ __launch_bounds__(TPB) void s1c_gemm_kernel(
        const int* __restrict__ row, const int* __restrict__ col,
        const int* __restrict__ counts, const int* __restrict__ bsum,
        int E, int nblk, int nbuck,
        int* __restrict__ bucketed,
        const float* __restrict__ x, const float* __restrict__ W1,
        unsigned short* __restrict__ h1b, int N, int nbg) {
    // unioned LDS: scatter uses 12352 B, gemm uses 10240 B (w1s stride-20)
    __shared__ __align__(16) char sbuf[2048 + 2048 + 8192 + 64];
    int* slhist = (int*)sbuf;                               // 512 ints (cursor)
    int* sgd    = (int*)(sbuf + 2048);                      // 512 ints
    unsigned short* ssidx = (unsigned short*)(sbuf + 4096); // 4096 ushort
    int* swtot  = (int*)(sbuf + 4096 + 8192);               // 4 ints
    float* w1s  = (float*)sbuf;                             // gemm: 128x20 f32

    int b = (int)blockIdx.x, t = threadIdx.x;
    int M = min(nblk, nbg);
    int role, id;
    if (b < 2 * M) { role = b & 1; id = b >> 1; }
    else           { role = (nblk > nbg) ? 0 : 1; id = b - M; }

    if (role == 0) {                         // block-local counting sort
        int e0 = id * CHUNK;
        int nE = min(CHUNK, E - e0);
        int Ltot = nbuck * nblk;
        int lane = t & 63, w = t >> 6;
        int bk0 = 2 * t, bk1 = 2 * t + 1;
        // per-bin counts for this chunk from global-scan differences
        int cb0 = 0, cb1 = 0, c0 = 0, c1 = 0;
        if (bk0 < nbuck) {
            int f = bk0 * nblk + id;
            cb0 = cbase_at(counts, bsum, f);
            int nx = (f + 1 < Ltot) ? cbase_at(counts, bsum, f + 1) : E;
            c0 = nx - cb0;
        }
        if (bk1 < nbuck) {
            int f = bk1 * nblk + id;
            cb1 = cbase_at(counts, bsum, f);
            int nx = (f + 1 < Ltot) ? cbase_at(counts, bsum, f + 1) : E;
            c1 = nx - cb1;
        }
        int s = c0 + c1;
        // wave inclusive scan of s over 64 lanes (bin order == thread order)
        int v = s;
#pragma unroll
        for (int d = 1; d < 64; d <<= 1) {
            int u2 = __shfl_up(v, d, 64);
            if (lane >= d) v += u2;
        }
        if (lane == 63) swtot[w] = v;
        __syncthreads();
        int wbase = 0;
#pragma unroll
        for (int i = 0; i < 4; ++i) wbase += (i < w) ? swtot[i] : 0;
        int o0 = wbase + v - s;              // local exclusive start of bk0
        int o1 = o0 + c0;
        if (bk0 < nbuck) { slhist[bk0] = o0; sgd[bk0] = cb0 - o0; }
        if (bk1 < nbuck) { slhist[bk1] = o1; sgd[bk1] = cb1 - o1; }
        __syncthreads();
        // scatter chunk-local indices into sorted order
        for (int i = t; i < nE; i += TPB) {
            int c = col[e0 + i];
            int lp = atomicAdd(&slhist[c >> BK_SHIFT], 1);     // LDS atomic
            ssidx[lp] = (unsigned short)i;
        }
        __syncthreads();
        // write out in bucket order -> runs of consecutive addresses
        for (int j = t; j < nE; j += TPB) {
            int i = ssidx[j];
            int c = col[e0 + i];                               // L1/L2-hot
            int r = row[e0 + i];
            bucketed[sgd[c >> BK_SHIFT] + j] = ((c & (NPB - 1)) << 18) | r;
        }
        return;
    }
    // gemm: h1b[n] = bf16(x[n] @ W1).  4 threads/node, thread q covers
    // k in {16i+4q+j}; per-i loads are 64B-line coalesced across q.
    for (int i = t; i < 128 * 16; i += TPB)
        w1s[(i >> 4) * W1S + (i & 15)] = W1[i];
    __syncthreads();
    int g = t >> 2, q = t & 3;
    int n = id * 64 + g;
    int nc = min(n, N - 1);
    const float4* xr = (const float4*)(x + (size_t)nc * 128);
    float4 xv[8];
#pragma unroll
    for (int i = 0; i < 8; ++i) xv[i] = xr[i * 4 + q];   // 8 loads in flight
    float acc[16];
#pragma unroll
    for (int k = 0; k < 16; ++k) acc[k] = 0.f;
#pragma unroll
    for (int i = 0; i < 8; ++i) {
        float xj[4] = {xv[i].x, xv[i].y, xv[i].z, xv[i].w};
#pragma unroll
        for (int j = 0; j < 4; ++j) {
            int k = i * 16 + q * 4 + j;
            const float4* w4 = (const float4*)&w1s[k * W1S];
            float4 wa = w4[0], wb = w4[1], wc = w4[2], wd = w4[3];
            float xc = xj[j];
            acc[0]  = fmaf(xc, wa.x, acc[0]);  acc[1]  = fmaf(xc, wa.y, acc[1]);
            acc[2]  = fmaf(xc, wa.z, acc[2]);  acc[3]  = fmaf(xc, wa.w, acc[3]);
            acc[4]  = fmaf(xc, wb.x, acc[4]);  acc[5]  = fmaf(xc, wb.y, acc[5]);
            acc[6]  = fmaf(xc, wb.z, acc[6]);  acc[7]  = fmaf(xc, wb.w, acc[7]);
            acc[8]  = fmaf(xc, wc.x, acc[8]);  acc[9]  = fmaf(xc, wc.y, acc[9]);
            acc[10] = fmaf(xc, wc.z, acc[10]); acc[11] = fmaf(xc, wc.w, acc[11]);
            acc[12] = fmaf(xc, wd.x, acc[12]); acc[13] = fmaf(xc, wd.y, acc[13]);
            acc[14] = fmaf(xc, wd.z, acc[14]); acc[15] = fmaf(xc, wd.w, acc[15]);
        }
    }
    // butterfly-reduce acc across the 4 K-split lanes
#pragma unroll
    for (int d = 1; d < 4; d <<= 1) {
#pragma unroll
        for (int k = 0; k < 16; ++k) acc[k] += __shfl_xor(acc[k], d, 4);
    }
    if (n < N) {                             // lane q stores feats 4q..4q+3
        unsigned int u0 = (unsigned int)f2bf(acc[4 * q]) |
                          ((unsigned int)f2bf(acc[4 * q + 1]) << 16);
        unsigned int u1 = (unsigned int)f2bf(acc[4 * q + 2]) |
                          ((unsigned int)f2bf(acc[4 * q + 3]) << 16);
        *(uint2*)&h1b[(size_t)n * 16 + 4 * q] = make_uint2(u0, u1);
    }
}

// S2: one block per 512-node bucket: counting sort, emit csr/offs/dinv,
// h1p = bf16(dinv * h1b).
__global__ __launch_bounds__(TPB) void sort_kernel(
        const int* __restrict__ bucketed,
        const int* __restrict__ counts, const int* __restrict__ bsum,
        int E, int nblk, int nbuck,
        int* __restrict__ csr, int* __restrict__ offs, float* __restrict__ dinv,
        const unsigned short* __restrict__ h1b, unsigned short* __restrict__ h1p, int N) {
    __shared__ int lhist[NPB];
    __shared__ int part[TPB];
    __shared__ float sdinv[NPB];
    int bk = blockIdx.x, t = threadIdx.x;
    int n0 = bk << BK_SHIFT;
    int n1 = min(n0 + NPB, N);
    int e0 = cbase_at(counts, bsum, bk * nblk);
    int e1 = (bk + 1 < nbuck) ? cbase_at(counts, bsum, (bk + 1) * nblk) : E;

    lhist[t] = 0; lhist[t + TPB] = 0;
    __syncthreads();
    for (int i = e0 + t; i < e1; i += TPB)
        atomicAdd(&lhist[bucketed[i] >> 18], 1);               // LDS atomic
    __syncthreads();

    int base = t * 2;
    int c0 = lhist[base], c1 = lhist[base + 1];
    int s = c0 + c1;
    part[t] = s;
    __syncthreads();
    for (int off = 1; off < TPB; off <<= 1) {
        int v = (t >= off) ? part[t - off] : 0;
        __syncthreads();
        part[t] += v;
        __syncthreads();
    }
    int o0 = e0 + part[t] - s;
    int o1 = o0 + c0;
    lhist[base] = o0; lhist[base + 1] = o1;
    sdinv[base]     = rsqrtf((float)c0 + 1.0f);
    sdinv[base + 1] = rsqrtf((float)c1 + 1.0f);
    int n = n0 + base;
    if (n + 0 < N) { offs[n + 0] = o0; dinv[n + 0] = sdinv[base]; }
    if (n + 1 < N) { offs[n + 1] = o1; dinv[n + 1] = sdinv[base + 1]; }
    __syncthreads();

    for (int i = e0 + t; i < e1; i += TPB) {
        int v = bucketed[i];
        int pos = atomicAdd(&lhist[v >> 18], 1);               // LDS atomic
        csr[pos] = v & 0x3FFFF;
    }
    int nq = (n1 - n0) * 4;                  // one quad (4 feats) per i
    for (int i = t; i < nq; i += TPB) {
        float dv = sdinv[i >> 2];
        uint2 u = ((const uint2*)h1b)[(size_t)n0 * 4 + i];
        float f0 = bf2f((unsigned short)(u.x & 0xffff));
        float f1 = bf2f((unsigned short)(u.x >> 16));
        float f2 = bf2f((unsigned short)(u.y & 0xffff));
        float f3 = bf2f((unsigned short)(u.y >> 16));
        ((ushort4*)h1p)[(size_t)n0 * 4 + i] =
            make_ushort4(f2bf(f0 * dv), f2bf(f1 * dv), f2bf(f2 * dv), f2bf(f3 * dv));
    }
    if (bk == 0 && t == 0) offs[N] = E;
}

// gather1: 16 lanes/node, uint4 gathers: lane l -> edge slot (l>>1), half-row
// (l&1).  Per 16-edge csr window: 2 predicated gather loads per lane (R19:
// tail loads branch-skipped, ~47% request reduction).  8-lane tree reduce;
// lanes 0/1 finalize 8 feats each.
// h2p[c] = bf16( dinv[c]*relu( dinv[c]*(sum h1p[src] + h1p[c]) + b1 ) )
__global__ __launch_bounds__(TPB) void gather1_kernel(const int* __restrict__ csr,
                                                      const int* __restrict__ offs,
                                                      const unsigned short* __restrict__ h1p,
                                                      const float* __restrict__ dinv,
                                                      const float* __restrict__ b1,
                                                      unsigned short* __restrict__ h2p, int N) {
    int t = threadIdx.x;
    int c = blockIdx.x * 16 + (t >> 4);
    int l = t & 15;
    int half = l & 1;                        // which 8-feature half-row
    int sub  = l >> 1;                       // edge slot 0..7
    if (c >= N) return;
    int p0 = offs[c], p1 = offs[c + 1];
    float a[8];
#pragma unroll
    for (int k = 0; k < 8; ++k) a[k] = 0.f;
    for (int p = p0; p < p1; p += 16) {
        int s16 = csr[min(p + l, p1 - 1)];
        int rem = p1 - p;
        uint4 u0 = make_uint4(0, 0, 0, 0), u1 = make_uint4(0, 0, 0, 0);
        {
            int e = sub;
            int src = __shfl(s16, e, 16);
            if (e < rem) u0 = *(const uint4*)&h1p[(size_t)src * 16 + 8 * half];
        }
        {
            int e = 8 + sub;
            int src = __shfl(s16, e, 16);
            if (e < rem) u1 = *(const uint4*)&h1p[(size_t)src * 16 + 8 * half];
        }
        bfacc8(u0, a);
        bfacc8(u1, a);
    }
#pragma unroll
    for (int d = 2; d < 16; d <<= 1) {
#pragma unroll
        for (int k = 0; k < 8; ++k) a[k] += __shfl_xor(a[k], d, 16);
    }
    if (l < 2) {                             // l==half here
        float dc = dinv[c];
        uint4 sv = *(const uint4*)&h1p[(size_t)c * 16 + 8 * l];
        float sf[8];
        bfunp8(sv, sf);
        unsigned int uo[4];
#pragma unroll
        for (int q = 0; q < 4; ++q) {
            float r0 = fmaf(dc, a[2 * q] + sf[2 * q], b1[8 * l + 2 * q]);
            float r1 = fmaf(dc, a[2 * q + 1] + sf[2 * q + 1], b1[8 * l + 2 * q + 1]);
            r0 = dc * fmaxf(r0, 0.f);
            r1 = dc * fmaxf(r1, 0.f);
            uo[q] = (unsigned int)f2bf(r0) | ((unsigned int)f2bf(r1) << 16);
        }
        *(uint4*)&h2p[(size_t)c * 16 + 8 * l] = make_uint4(uo[0], uo[1], uo[2], uo[3]);
    }
}

// gather2f: fused gather2 + W2 matmul + sorted-batch pooling.  Block = 64 nodes.
// Phase 1: 16 groups x 16 lanes gather a2 rows (4 nodes/group, predicated
// uint4 gathers as in gather1) into LDS asT.
// Phase 2: wave w: 64 lanes = output dims, 16 nodes from asT, W2 slice in regs,
//          run-accumulate; uniform-batch blocks pool in LDS, flush 64 atomics.
__global__ __launch_bounds__(TPB) void gather2f_kernel(
        const int* __restrict__ csr, const int* __restrict__ offs,
        const unsigned short* __restrict__ h2p, const float* __restrict__ dinv,
        const float* __restrict__ W2, const float* __restrict__ b2,
        const int* __restrict__ batch, float* __restrict__ out, int N) {
    __shared__ float w2s[16 * 64];
    __shared__ float asT[64 * 17];
    __shared__ float pool[64];
    int t = threadIdx.x;
    for (int i = t; i < 16 * 64; i += TPB) w2s[i] = W2[i];
    if (t < 64) pool[t] = 0.f;

    int n0 = blockIdx.x * 64;
    int nLast = min(n0 + 63, N - 1);
    int g0 = batch[n0];
    bool uniform = (batch[nLast] == g0);     // batch sorted

    // phase 1: gather (4 nodes per 16-lane group, predicated uint4 loads)
    int grp = t >> 4, l = t & 15;
    int half = l & 1, sub = l >> 1;
#pragma unroll 1
    for (int it = 0; it < 4; ++it) {
        int m = grp * 4 + it;
        int c = n0 + m;
        if (c < N) {
            int p0 = offs[c], p1 = offs[c + 1];
            float a[8];
#pragma unroll
            for (int k = 0; k < 8; ++k) a[k] = 0.f;
            for (int p = p0; p < p1; p += 16) {
                int s16 = csr[min(p + l, p1 - 1)];
                int rem = p1 - p;
                uint4 u0 = make_uint4(0, 0, 0, 0), u1 = make_uint4(0, 0, 0, 0);
                {
                    int e = sub;
                    int src = __shfl(s16, e, 16);
                    if (e < rem) u0 = *(const uint4*)&h2p[(size_t)src * 16 + 8 * half];
                }
                {
                    int e = 8 + sub;
                    int src = __shfl(s16, e, 16);
                    if (e < rem) u1 = *(const uint4*)&h2p[(size_t)src * 16 + 8 * half];
                }
                bfacc8(u0, a);
                bfacc8(u1, a);
            }
#pragma unroll
            for (int d = 2; d < 16; d <<= 1) {
#pragma unroll
                for (int k = 0; k < 8; ++k) a[k] += __shfl_xor(a[k], d, 16);
            }
            if (l < 2) {
                float dc = dinv[c];
                uint4 sv = *(const uint4*)&h2p[(size_t)c * 16 + 8 * l];
                float sf[8];
                bfunp8(sv, sf);
#pragma unroll
                for (int k = 0; k < 8; ++k)
                    asT[m * 17 + 8 * l + k] = dc * (a[k] + sf[k]);
            }
        }
    }
    __syncthreads();

    // phase 2: wave w covers nodes n0+16w .. n0+16w+15
    int wave = t >> 6, j = t & 63;
    float w2reg[16];
#pragma unroll
    for (int kx = 0; kx < 16; ++kx) w2reg[kx] = w2s[kx * 64 + j];
    float b2j = b2[j];
    float val = 0.f;
    int g_cur = -1;
#pragma unroll 1
    for (int mi = 0; mi < 16; ++mi) {
        int m = wave * 16 + mi;
        int c = n0 + m;
        if (c >= N) break;
        const float* ar = &asT[m * 17];
        float y = b2j;
#pragma unroll
        for (int kx = 0; kx < 16; ++kx) y = fmaf(ar[kx], w2reg[kx], y);
        if (uniform) {
            val += y;
        } else {
            int g = batch[c];
            if (g != g_cur) {
                if (g_cur >= 0) atomicAdd(&out[(size_t)g_cur * 64 + j], val);
                val = 0.f;
                g_cur = g;
            }
            val += y;
        }
    }
    if (uniform) {
        atomicAdd(&pool[j], val);            // LDS, 4-way per address
        __syncthreads();
        if (t < 64) atomicAdd(&out[(size_t)g0 * 64 + t], pool[t]);
    } else {
        if (g_cur >= 0) atomicAdd(&out[(size_t)g_cur * 64 + j], val);
    }
}

static inline size_t align64(size_t v) { return (v + 63) & ~(size_t)63; }

extern "C" void kernel_launch(void* const* d_in, const int* in_sizes, int n_in,
                              void* d_out, int out_size, void* d_ws, size_t ws_size,
                              hipStream_t stream) {
    const float* x     = (const float*)d_in[0];
    const int*   ei    = (const int*)d_in[1];
    const int*   batch = (const int*)d_in[2];
    const float* W1    = (const float*)d_in[3];
    const float* b1    = (const float*)d_in[4];
    const float* W2    = (const float*)d_in[5];
    const float* b2    = (const float*)d_in[6];

    const int N = in_sizes[0] / 128;
    const int E = in_sizes[1] / 2;
    const int* row = ei;        // edge_index[0]
    const int* col = ei + E;    // edge_index[1]

    const int NBLK  = (E + CHUNK - 1) / CHUNK;       // 782
    const int NBUCK = (N + NPB - 1) / NPB;           // 391 (<=512)
    const int L     = NBUCK * NBLK;                  // 305762
    const int NBS   = (L + TPB - 1) / TPB;           // 1195 (<=2048 for scan2)
    const int NBG   = (N + 63) / 64;                 // 3125 gemm blocks

    char* p = (char*)d_ws;
    int*            counts   = (int*)p;            p += align64((size_t)L * 4);
    int*            bsum     = (int*)p;            p += align64(2048 * 4);
    int*            bucketed = (int*)p;            p += align64((size_t)E * 4);
    int*            csr      = (int*)p;            p += align64((size_t)E * 4);
    int*            offs     = (int*)p;            p += align64((size_t)(N + 1) * 4);
    float*          dinv     = (float*)p;          p += align64((size_t)N * 4);
    unsigned short* h1b      = (unsigned short*)p; p += align64((size_t)N * 16 * 2);
    unsigned short* h1p      = (unsigned short*)p; p += align64((size_t)N * 16 * 2);
    unsigned short* h2p      = (unsigned short*)p; p += align64((size_t)N * 16 * 2);
    float*          out      = (float*)d_out;

    hipMemsetAsync(out, 0, (size_t)out_size * sizeof(float), stream);

    hist_kernel<<<NBLK, TPB, 0, stream>>>(col, counts, E, NBLK, NBUCK);
    scan1_kernel<<<NBS, TPB, 0, stream>>>(counts, counts, bsum, L);
    scan2_kernel<<<1, 1024, 0, stream>>>(bsum, NBS);
    s1c_gemm_kernel<<<NBLK + NBG, TPB, 0, stream>>>(row, col, counts, bsum,
                                                    E, NBLK, NBUCK,
                                                    bucketed, x, W1, h1b, N, NBG);
    sort_kernel<<<NBUCK, TPB, 0, stream>>>(bucketed, counts, bsum, E, NBLK, NBUCK,
                                           csr, offs, dinv, h1b, h1p, N);
    gather1_kernel<<<(N + 15) / 16, TPB, 0, stream>>>(csr, offs, h1p, dinv, b1, h2p, N);
    gather2f_kernel<<<(N + 63) / 64, TPB, 0, stream>>>(csr, offs, h2p, dinv,
                                                       W2, b2, batch, out, N);
}

// Round 9
// 331.423 us; speedup vs baseline: 1.7827x; 1.0272x over previous
//
#include <hip/hip_runtime.h>

// 2-layer GCN, CSR-gather, bf16 payloads, zero global atomics.
//   hist(512-node buckets) -> scan1/scan2 -> [scatter ∥ gemm, 1:1] -> sort
//   -> gather1 -> gather2f (gather + W2 matmul + pooled output, fused).
// Kept: 1:1 scatter/gemm interleave (R9), 512-node buckets, packed 1-int
// bucket entries, bf16 h1 (R10), scan3g folded into consumers (R10),
// final fused into gather2 (R10), sorted coalesced bucket writes (R12),
// scan-diff counts + shfl scan + LDS union (R13), uint4 gathers (R13),
// K-split coalesced gemm loads (R16), predicated gather loads (R19).
// R18 history: global-atomic CSR REFUTED (random 4B stores, WRITE 208MB).
// R19 history: request-count cut was NEUTRAL -> gathers are latency-bound,
//   not request-rate-bound.
// R20: (a) gathers restructured for in-flight depth: one 32-edge round
//   (both csr window loads upfront, 4 predicated uint4 gathers per lane
//   issued back-to-back) replaces two serial 16-edge windows.  deg+1~=17
//   -> a single round covers ~all nodes; the serial window dependency
//   disappears.  (b) 2-node/thread gemm (R17, proven standalone) restored
//   inside the combined kernel: each W1 ds_read_b128 feeds 32 FMA (halves
//   the LDS-issue floor), gemm blocks 3125->1563.  VGPR ~120 < 128.

#define TPB 256
#define CHUNK 4096          // edges per stage-1 block
#define BK_SHIFT 9
#define NPB 512             // nodes per bucket = 1 << BK_SHIFT
#define W1S 20              // w1s k-row stride in floats (bank-spread pad)

__device__ __forceinline__ float bf2f(unsigned short u) {
    union { unsigned int i; float f; } v; v.i = ((unsigned int)u) << 16; return v.f;
}
__device__ __forceinline__ unsigned short f2bf(float f) {
    union { float f; unsigned int i; } v; v.f = f;
    unsigned int r = v.i + 0x7fff + ((v.i >> 16) & 1);   // RNE
    return (unsigned short)(r >> 16);
}
// accumulate 8 bf16 (one uint4) into a[0..7]
__device__ __forceinline__ void bfacc8(uint4 v, float* a) {
    union { unsigned int i; float f; } lo, hi;
    lo.i = v.x << 16; hi.i = v.x & 0xffff0000u; a[0] += lo.f; a[1] += hi.f;
    lo.i = v.y << 16; hi.i = v.y & 0xffff0000u; a[2] += lo.f; a[3] += hi.f;
    lo.i = v.z << 16; hi.i = v.z & 0xffff0000u; a[4] += lo.f; a[5] += hi.f;
    lo.i = v.w << 16; hi.i = v.w & 0xffff0000u; a[6] += lo.f; a[7] += hi.f;
}
__device__ __forceinline__ void bfunp8(uint4 v, float* a) {
    union { unsigned int i; float f; } lo, hi;
    lo.i = v.x << 16; hi.i = v.x & 0xffff0000u; a[0] = lo.f; a[1] = hi.f;
    lo.i = v.y << 16; hi.i = v.y & 0xffff0000u; a[2] = lo.f; a[3] = hi.f;
    lo.i = v.z << 16; hi.i = v.z & 0xffff0000u; a[4] = lo.f; a[5] = hi.f;
    lo.i = v.w << 16; hi.i = v.w & 0xffff0000u; a[6] = lo.f; a[7] = hi.f;
}

// one 32-edge gather round for node c (16 lanes), predicated uint4 loads.
// lane l: half = l&1 (8-feature half-row), sub = l>>1 (edge slot).
// Covers edges p+{sub, 8+sub, 16+sub, 24+sub}; all 4 loads issue before
// any accumulate -> 4-deep in-flight per lane (R20).
__device__ __forceinline__ void gather32(const int* __restrict__ csr,
                                         const unsigned short* __restrict__ src_feat,
                                         int p, int p1, int l, int half, int sub,
                                         float* a) {
    int s_lo = csr[min(p + l, p1 - 1)];
    int s_hi = csr[min(p + 16 + l, p1 - 1)];
    int rem = p1 - p;
    int e0 = sub, e1 = 8 + sub, e2 = 16 + sub, e3 = 24 + sub;
    int src0 = __shfl(s_lo, e0, 16);
    int src1 = __shfl(s_lo, e1, 16);
    int src2 = __shfl(s_hi, e2 - 16, 16);
    int src3 = __shfl(s_hi, e3 - 16, 16);
    uint4 u0 = make_uint4(0, 0, 0, 0), u1 = make_uint4(0, 0, 0, 0);
    uint4 u2 = make_uint4(0, 0, 0, 0), u3 = make_uint4(0, 0, 0, 0);
    if (e0 < rem) u0 = *(const uint4*)&src_feat[(size_t)src0 * 16 + 8 * half];
    if (e1 < rem) u1 = *(const uint4*)&src_feat[(size_t)src1 * 16 + 8 * half];
    if (e2 < rem) u2 = *(const uint4*)&src_feat[(size_t)src2 * 16 + 8 * half];
    if (e3 < rem) u3 = *(const uint4*)&src_feat[(size_t)src3 * 16 + 8 * half];
    bfacc8(u0, a);
    bfacc8(u1, a);
    bfacc8(u2, a);
    bfacc8(u3, a);
}

// S1a: counts[bk*nblk + blk] = #edges in block blk with col>>9 == bk
__global__ __launch_bounds__(TPB) void hist_kernel(const int* __restrict__ col,
                                                   int* __restrict__ counts,
                                                   int E, int nblk, int nbuck) {
    __shared__ int hist[512];
    int t = threadIdx.x;
    for (int i = t; i < nbuck; i += TPB) hist[i] = 0;
    __syncthreads();
    int e0 = blockIdx.x * CHUNK;
    for (int i = t; i < CHUNK; i += TPB) {
        int e = e0 + i;
        if (e < E) atomicAdd(&hist[col[e] >> BK_SHIFT], 1);   // LDS atomic
    }
    __syncthreads();
    for (int i = t; i < nbuck; i += TPB) counts[i * nblk + blockIdx.x] = hist[i];
}

// scan1: per-256-block exclusive scan (counts in place), bsum[b]=block total
__global__ __launch_bounds__(TPB) void scan1_kernel(const int* __restrict__ in,
                                                    int* __restrict__ out,
                                                    int* __restrict__ bsum, int L) {
    __shared__ int s[TPB];
    int t = threadIdx.x;
    int i = blockIdx.x * TPB + t;
    int d = (i < L) ? in[i] : 0;
    s[t] = d; __syncthreads();
    for (int off = 1; off < TPB; off <<= 1) {
        int v = (t >= off) ? s[t - off] : 0;
        __syncthreads();
        s[t] += v;
        __syncthreads();
    }
    if (i < L) out[i] = s[t] - d;
    if (t == TPB - 1) bsum[blockIdx.x] = s[t];
}

// scan2: single-block exclusive scan of up to 2048 block sums (2 elems/thread)
__global__ __launch_bounds__(1024) void scan2_kernel(int* __restrict__ bsum, int nb) {
    __shared__ int s[1024];
    int t = threadIdx.x;
    int i0 = t * 2, i1 = t * 2 + 1;
    int v0 = (i0 < nb) ? bsum[i0] : 0;
    int v1 = (i1 < nb) ? bsum[i1] : 0;
    int pv = v0 + v1;
    s[t] = pv; __syncthreads();
    for (int off = 1; off < 1024; off <<= 1) {
        int u = (t >= off) ? s[t - off] : 0;
        __syncthreads();
        s[t] += u;
        __syncthreads();
    }
    int exc = s[t] - pv;
    if (i0 < nb) bsum[i0] = exc;
    if (i1 < nb) bsum[i1] = exc + v0;
}

// cbase[f] = counts[f] + bsum[f>>8]   (scan3g folded into consumers)
__device__ __forceinline__ int cbase_at(const int* counts, const int* bsum, int f) {
    return counts[f] + bsum[f >> 8];
}

// S1c ∥ gemm, block-interleaved 1:1.
// Scatter: counts from scan diffs, shfl-scan local offsets, LDS counting
//   sort, bucket-ordered coalesced writes.
// Gemm: 4 threads/node K-split, 2 nodes/thread (R17/R20): each W1
//   ds_read_b128 feeds 32 FMA; 16 coalesced x loads upfront.
__global__ __launch_bounds__(TPB) void s1c_gemm_kernel(
        const int* __restrict__ row, const int* __restrict__ col,
        const int* __restrict__ counts, const int* __restrict__ bsum,
        int E, int nblk, int nbuck,
        int* __restrict__ bucketed,
        const float* __restrict__ x, const float* __restrict__ W1,
        unsigned short* __restrict__ h1b, int N, int nbg) {
    // unioned LDS: scatter uses 12352 B, gemm uses 10240 B (w1s stride-20)
    __shared__ __align__(16) char sbuf[2048 + 2048 + 8192 + 64];
    int* slhist = (int*)sbuf;                               // 512 ints (cursor)
    int* sgd    = (int*)(sbuf + 2048);                      // 512 ints
    unsigned short* ssidx = (unsigned short*)(sbuf + 4096); // 4096 ushort
    int* swtot  = (int*)(sbuf + 4096 + 8192);               // 4 ints
    float* w1s  = (float*)sbuf;                             // gemm: 128x20 f32

    int b = (int)blockIdx.x, t = threadIdx.x;
    int M = min(nblk, nbg);
    int role, id;
    if (b < 2 * M) { role = b & 1; id = b >> 1; }
    else           { role = (nblk > nbg) ? 0 : 1; id = b - M; }

    if (role == 0) {                         // block-local counting sort
        int e0 = id * CHUNK;
        int nE = min(CHUNK, E - e0);
        int Ltot = nbuck * nblk;
        int lane = t & 63, w = t >> 6;
        int bk0 = 2 * t, bk1 = 2 * t + 1;
        // per-bin counts for this chunk from global-scan differences
        int cb0 = 0, cb1 = 0, c0 = 0, c1 = 0;
        if (bk0 < nbuck) {
            int f = bk0 * nblk + id;
            cb0 = cbase_at(counts, bsum, f);
            int nx = (f + 1 < Ltot) ? cbase_at(counts, bsum, f + 1) : E;
            c0 = nx - cb0;
        }
        if (bk1 < nbuck) {
            int f = bk1 * nblk + id;
            cb1 = cbase_at(counts, bsum, f);
            int nx = (f + 1 < Ltot) ? cbase_at(counts, bsum, f + 1) : E;
            c1 = nx - cb1;
        }
        int s = c0 + c1;
        // wave inclusive scan of s over 64 lanes (bin order == thread order)
        int v = s;
#pragma unroll
        for (int d = 1; d < 64; d <<= 1) {
            int u2 = __shfl_up(v, d, 64);
            if (lane >= d) v += u2;
        }
        if (lane == 63) swtot[w] = v;
        __syncthreads();
        int wbase = 0;
#pragma unroll
        for (int i = 0; i < 4; ++i) wbase += (i < w) ? swtot[i] : 0;
        int o0 = wbase + v - s;              // local exclusive start of bk0
        int o1 = o0 + c0;
        if (bk0 < nbuck) { slhist[bk0] = o0; sgd[bk0] = cb0 - o0; }
        if (bk1 < nbuck) { slhist[bk1] = o1; sgd[bk1] = cb1 - o1; }
        __syncthreads();
        // scatter chunk-local indices into sorted order
        for (int i = t; i < nE; i += TPB) {
            int c = col[e0 + i];
            int lp = atomicAdd(&slhist[c >> BK_SHIFT], 1);     // LDS atomic
            ssidx[lp] = (unsigned short)i;
        }
        __syncthreads();
        // write out in bucket order -> runs of consecutive addresses
        for (int j = t; j < nE; j += TPB) {
            int i = ssidx[j];
            int c = col[e0 + i];                               // L1/L2-hot
            int r = row[e0 + i];
            bucketed[sgd[c >> BK_SHIFT] + j] = ((c & (NPB - 1)) << 18) | r;
        }
        return;
    }
    // gemm: h1b[n] = bf16(x[n] @ W1).  4 threads/node K-split, 2 nodes/thread.
    for (int i = t; i < 128 * 16; i += TPB)
        w1s[(i >> 4) * W1S + (i & 15)] = W1[i];
    __syncthreads();
    int g = t >> 2, q = t & 3;
    int nA = id * 128 + g;
    int nB = nA + 64;
    int nAc = min(nA, N - 1), nBc = min(nB, N - 1);
    const float4* xA = (const float4*)(x + (size_t)nAc * 128);
    const float4* xB = (const float4*)(x + (size_t)nBc * 128);
    float4 xvA[8], xvB[8];
#pragma unroll
    for (int i = 0; i < 8; ++i) xvA[i] = xA[i * 4 + q];   // 16 loads in flight
#pragma unroll
    for (int i = 0; i < 8; ++i) xvB[i] = xB[i * 4 + q];
    float accA[16], accB[16];
#pragma unroll
    for (int k = 0; k < 16; ++k) { accA[k] = 0.f; accB[k] = 0.f; }
#pragma unroll
    for (int i = 0; i < 8; ++i) {
        float xjA[4] = {xvA[i].x, xvA[i].y, xvA[i].z, xvA[i].w};
        float xjB[4] = {xvB[i].x, xvB[i].y, xvB[i].z, xvB[i].w};
#pragma unroll
        for (int j = 0; j < 4; ++j) {
            int k = i * 16 + q * 4 + j;
            const float4* w4 = (const float4*)&w1s[k * W1S];
            float4 wa = w4[0], wb = w4[1], wc = w4[2], wd = w4[3];
            float xa = xjA[j], xb = xjB[j];
            accA[0]  = fmaf(xa, wa.x, accA[0]);  accA[1]  = fmaf(xa, wa.y, accA[1]);
            accA[2]  = fmaf(xa, wa.z, accA[2]);  accA[3]  = fmaf(xa, wa.w, accA[3]);
            accA[4]  = fmaf(xa, wb.x, accA[4]);  accA[5]  = fmaf(xa, wb.y, accA[5]);
            accA[6]  = fmaf(xa, wb.z, accA[6]);  accA[7]  = fmaf(xa, wb.w, accA[7]);
            accA[8]  = fmaf(xa, wc.x, accA[8]);  accA[9]  = fmaf(xa, wc.y, accA[9]);
            accA[10] = fmaf(xa, wc.z, accA[10]); accA[11] = fmaf(xa, wc.w, accA[11]);
            accA[12] = fmaf(xa, wd.x, accA[12]); accA[13] = fmaf(xa, wd.y, accA[13]);
            accA[14] = fmaf(xa, wd.z, accA[14]); accA[15] = fmaf(xa, wd.w, accA[15]);
            accB[0]  = fmaf(xb, wa.x, accB[0]);  accB[1]  = fmaf(xb, wa.y, accB[1]);
            accB[2]  = fmaf(xb, wa.z, accB[2]);  accB[3]  = fmaf(xb, wa.w, accB[3]);
            accB[4]  = fmaf(xb, wb.x, accB[4]);  accB[5]  = fmaf(xb, wb.y, accB[5]);
            accB[6]  = fmaf(xb, wb.z, accB[6]);  accB[7]  = fmaf(xb, wb.w, accB[7]);
            accB[8]  = fmaf(xb, wc.x, accB[8]);  accB[9]  = fmaf(xb, wc.y, accB[9]);
            accB[10] = fmaf(xb, wc.z, accB[10]); accB[11] = fmaf(xb, wc.w, accB[11]);
            accB[12] = fmaf(xb, wd.x, accB[12]); accB[13] = fmaf(xb, wd.y, accB[13]);
            accB[14] = fmaf(xb, wd.z, accB[14]); accB[15] = fmaf(xb, wd.w, accB[15]);
        }
    }
    // butterfly-reduce both accs across the 4 K-split lanes
#pragma unroll
    for (int d = 1; d < 4; d <<= 1) {
#pragma unroll
        for (int k = 0; k < 16; ++k) {
            accA[k] += __shfl_xor(accA[k], d, 4);
            accB[k] += __shfl_xor(accB[k], d, 4);
        }
    }
    if (nA < N) {                            // lane q stores feats 4q..4q+3
        unsigned int u0 = (unsigned int)f2bf(accA[4 * q]) |
                          ((unsigned int)f2bf(accA[4 * q + 1]) << 16);
        unsigned int u1 = (unsigned int)f2bf(accA[4 * q + 2]) |
                          ((unsigned int)f2bf(accA[4 * q + 3]) << 16);
        *(uint2*)&h1b[(size_t)nA * 16 + 4 * q] = make_uint2(u0, u1);
    }
    if (nB < N) {
        unsigned int u0 = (unsigned int)f2bf(accB[4 * q]) |
                          ((unsigned int)f2bf(accB[4 * q + 1]) << 16);
        unsigned int u1 = (unsigned int)f2bf(accB[4 * q + 2]) |
                          ((unsigned int)f2bf(accB[4 * q + 3]) << 16);
        *(uint2*)&h1b[(size_t)nB * 16 + 4 * q] = make_uint2(u0, u1);
    }
}

// S2: one block per 512-node bucket: counting sort, emit csr/offs/dinv,
// h1p = bf16(dinv * h1b).
__global__ __launch_bounds__(TPB) void sort_kernel(
        const int* __restrict__ bucketed,
        const int* __restrict__ counts, const int* __restrict__ bsum,
        int E, int nblk, int nbuck,
        int* __restrict__ csr, int* __restrict__ offs, float* __restrict__ dinv,
        const unsigned short* __restrict__ h1b, unsigned short* __restrict__ h1p, int N) {
    __shared__ int lhist[NPB];
    __shared__ int part[TPB];
    __shared__ float sdinv[NPB];
    int bk = blockIdx.x, t = threadIdx.x;
    int n0 = bk << BK_SHIFT;
    int n1 = min(n0 + NPB, N);
    int e0 = cbase_at(counts, bsum, bk * nblk);
    int e1 = (bk + 1 < nbuck) ? cbase_at(counts, bsum, (bk + 1) * nblk) : E;

    lhist[t] = 0; lhist[t + TPB] = 0;
    __syncthreads();
    for (int i = e0 + t; i < e1; i += TPB)
        atomicAdd(&lhist[bucketed[i] >> 18], 1);               // LDS atomic
    __syncthreads();

    int base = t * 2;
    int c0 = lhist[base], c1 = lhist[base + 1];
    int s = c0 + c1;
    part[t] = s;
    __syncthreads();
    for (int off = 1; off < TPB; off <<= 1) {
        int v = (t >= off) ? part[t - off] : 0;
        __syncthreads();
        part[t] += v;
        __syncthreads();
    }
    int o0 = e0 + part[t] - s;
    int o1 = o0 + c0;
    lhist[base] = o0; lhist[base + 1] = o1;
    sdinv[base]     = rsqrtf((float)c0 + 1.0f);
    sdinv[base + 1] = rsqrtf((float)c1 + 1.0f);
    int n = n0 + base;
    if (n + 0 < N) { offs[n + 0] = o0; dinv[n + 0] = sdinv[base]; }
    if (n + 1 < N) { offs[n + 1] = o1; dinv[n + 1] = sdinv[base + 1]; }
    __syncthreads();

    for (int i = e0 + t; i < e1; i += TPB) {
        int v = bucketed[i];
        int pos = atomicAdd(&lhist[v >> 18], 1);               // LDS atomic
        csr[pos] = v & 0x3FFFF;
    }
    int nq = (n1 - n0) * 4;                  // one quad (4 feats) per i
    for (int i = t; i < nq; i += TPB) {
        float dv = sdinv[i >> 2];
        uint2 u = ((const uint2*)h1b)[(size_t)n0 * 4 + i];
        float f0 = bf2f((unsigned short)(u.x & 0xffff));
        float f1 = bf2f((unsigned short)(u.x >> 16));
        float f2 = bf2f((unsigned short)(u.y & 0xffff));
        float f3 = bf2f((unsigned short)(u.y >> 16));
        ((ushort4*)h1p)[(size_t)n0 * 4 + i] =
            make_ushort4(f2bf(f0 * dv), f2bf(f1 * dv), f2bf(f2 * dv), f2bf(f3 * dv));
    }
    if (bk == 0 && t == 0) offs[N] = E;
}

// gather1: 16 lanes/node, 32-edge rounds (R20): both csr loads + 4
// predicated uint4 gathers in flight per lane before any accumulate.
// 8-lane tree reduce; lanes 0/1 finalize 8 feats each.
// h2p[c] = bf16( dinv[c]*relu( dinv[c]*(sum h1p[src] + h1p[c]) + b1 ) )
__global__ __launch_bounds__(TPB) void gather1_kernel(const int* __restrict__ csr,
                                                      const int* __restrict__ offs,
                                                      const unsigned short* __restrict__ h1p,
                                                      const float* __restrict__ dinv,
                                                      const float* __restrict__ b1,
                                                      unsigned short* __restrict__ h2p, int N) {
    int t = threadIdx.x;
    int c = blockIdx.x * 16 + (t >> 4);
    int l = t & 15;
    int half = l & 1;                        // which 8-feature half-row
    int sub  = l >> 1;                       // edge slot 0..7
    if (c >= N) return;
    int p0 = offs[c], p1 = offs[c + 1];
    float a[8];
#pragma unroll
    for (int k = 0; k < 8; ++k) a[k] = 0.f;
    for (int p = p0; p < p1; p += 32)
        gather32(csr, h1p, p, p1, l, half, sub, a);
#pragma unroll
    for (int d = 2; d < 16; d <<= 1) {
#pragma unroll
        for (int k = 0; k < 8; ++k) a[k] += __shfl_xor(a[k], d, 16);
    }
    if (l < 2) {                             // l==half here
        float dc = dinv[c];
        uint4 sv = *(const uint4*)&h1p[(size_t)c * 16 + 8 * l];
        float sf[8];
        bfunp8(sv, sf);
        unsigned int uo[4];
#pragma unroll
        for (int q = 0; q < 4; ++q) {
            float r0 = fmaf(dc, a[2 * q] + sf[2 * q], b1[8 * l + 2 * q]);
            float r1 = fmaf(dc, a[2 * q + 1] + sf[2 * q + 1], b1[8 * l + 2 * q + 1]);
            r0 = dc * fmaxf(r0, 0.f);
            r1 = dc * fmaxf(r1, 0.f);
            uo[q] = (unsigned int)f2bf(r0) | ((unsigned int)f2bf(r1) << 16);
        }
        *(uint4*)&h2p[(size_t)c * 16 + 8 * l] = make_uint4(uo[0], uo[1], uo[2], uo[3]);
    }
}

// gather2f: fused gather2 + W2 matmul + sorted-batch pooling.  Block = 64 nodes.
// Phase 1: 16 groups x 16 lanes gather a2 rows (4 nodes/group, 32-edge
// rounds as in gather1) into LDS asT.
// Phase 2: wave w: 64 lanes = output dims, 16 nodes from asT, W2 slice in regs,
//          run-accumulate; uniform-batch blocks pool in LDS, flush 64 atomics.
__global__ __launch_bounds__(TPB) void gather2f_kernel(
        const int* __restrict__ csr, const int* __restrict__ offs,
        const unsigned short* __restrict__ h2p, const float* __restrict__ dinv,
        const float* __restrict__ W2, const float* __restrict__ b2,
        const int* __restrict__ batch, float* __restrict__ out, int N) {
    __shared__ float w2s[16 * 64];
    __shared__ float asT[64 * 17];
    __shared__ float pool[64];
    int t = threadIdx.x;
    for (int i = t; i < 16 * 64; i += TPB) w2s[i] = W2[i];
    if (t < 64) pool[t] = 0.f;

    int n0 = blockIdx.x * 64;
    int nLast = min(n0 + 63, N - 1);
    int g0 = batch[n0];
    bool uniform = (batch[nLast] == g0);     // batch sorted

    // phase 1: gather (4 nodes per 16-lane group, 32-edge rounds)
    int grp = t >> 4, l = t & 15;
    int half = l & 1, sub = l >> 1;
#pragma unroll 1
    for (int it = 0; it < 4; ++it) {
        int m = grp * 4 + it;
        int c = n0 + m;
        if (c < N) {
            int p0 = offs[c], p1 = offs[c + 1];
            float a[8];
#pragma unroll
            for (int k = 0; k < 8; ++k) a[k] = 0.f;
            for (int p = p0; p < p1; p += 32)
                gather32(csr, h2p, p, p1, l, half, sub, a);
#pragma unroll
            for (int d = 2; d < 16; d <<= 1) {
#pragma unroll
                for (int k = 0; k < 8; ++k) a[k] += __shfl_xor(a[k], d, 16);
            }
            if (l < 2) {
                float dc = dinv[c];
                uint4 sv = *(const uint4*)&h2p[(size_t)c * 16 + 8 * l];
                float sf[8];
                bfunp8(sv, sf);
#pragma unroll
                for (int k = 0; k < 8; ++k)
                    asT[m * 17 + 8 * l + k] = dc * (a[k] + sf[k]);
            }
        }
    }
    __syncthreads();

    // phase 2: wave w covers nodes n0+16w .. n0+16w+15
    int wave = t >> 6, j = t & 63;
    float w2reg[16];
#pragma unroll
    for (int kx = 0; kx < 16; ++kx) w2reg[kx] = w2s[kx * 64 + j];
    float b2j = b2[j];
    float val = 0.f;
    int g_cur = -1;
#pragma unroll 1
    for (int mi = 0; mi < 16; ++mi) {
        int m = wave * 16 + mi;
        int c = n0 + m;
        if (c >= N) break;
        const float* ar = &asT[m * 17];
        float y = b2j;
#pragma unroll
        for (int kx = 0; kx < 16; ++kx) y = fmaf(ar[kx], w2reg[kx], y);
        if (uniform) {
            val += y;
        } else {
            int g = batch[c];
            if (g != g_cur) {
                if (g_cur >= 0) atomicAdd(&out[(size_t)g_cur * 64 + j], val);
                val = 0.f;
                g_cur = g;
            }
            val += y;
        }
    }
    if (uniform) {
        atomicAdd(&pool[j], val);            // LDS, 4-way per address
        __syncthreads();
        if (t < 64) atomicAdd(&out[(size_t)g0 * 64 + t], pool[t]);
    } else {
        if (g_cur >= 0) atomicAdd(&out[(size_t)g_cur * 64 + j], val);
    }
}

static inline size_t align64(size_t v) { return (v + 63) & ~(size_t)63; }

extern "C" void kernel_launch(void* const* d_in, const int* in_sizes, int n_in,
                              void* d_out, int out_size, void* d_ws, size_t ws_size,
                              hipStream_t stream) {
    const float* x     = (const float*)d_in[0];
    const int*   ei    = (const int*)d_in[1];
    const int*   batch = (const int*)d_in[2];
    const float* W1    = (const float*)d_in[3];
    const float* b1    = (const float*)d_in[4];
    const float* W2    = (const float*)d_in[5];
    const float* b2    = (const float*)d_in[6];

    const int N = in_sizes[0] / 128;
    const int E = in_sizes[1] / 2;
    const int* row = ei;        // edge_index[0]
    const int* col = ei + E;    // edge_index[1]

    const int NBLK  = (E + CHUNK - 1) / CHUNK;       // 782
    const int NBUCK = (N + NPB - 1) / NPB;           // 391 (<=512)
    const int L     = NBUCK * NBLK;                  // 305762
    const int NBS   = (L + TPB - 1) / TPB;           // 1195 (<=2048 for scan2)
    const int NBG   = (N + 127) / 128;               // 1563 gemm blocks

    char* p = (char*)d_ws;
    int*            counts   = (int*)p;            p += align64((size_t)L * 4);
    int*            bsum     = (int*)p;            p += align64(2048 * 4);
    int*            bucketed = (int*)p;            p += align64((size_t)E * 4);
    int*            csr      = (int*)p;            p += align64((size_t)E * 4);
    int*            offs     = (int*)p;            p += align64((size_t)(N + 1) * 4);
    float*          dinv     = (float*)p;          p += align64((size_t)N * 4);
    unsigned short* h1b      = (unsigned short*)p; p += align64((size_t)N * 16 * 2);
    unsigned short* h1p      = (unsigned short*)p; p += align64((size_t)N * 16 * 2);
    unsigned short* h2p      = (unsigned short*)p; p += align64((size_t)N * 16 * 2);
    float*          out      = (float*)d_out;

    hipMemsetAsync(out, 0, (size_t)out_size * sizeof(float), stream);

    hist_kernel<<<NBLK, TPB, 0, stream>>>(col, counts, E, NBLK, NBUCK);
    scan1_kernel<<<NBS, TPB, 0, stream>>>(counts, counts, bsum, L);
    scan2_kernel<<<1, 1024, 0, stream>>>(bsum, NBS);
    s1c_gemm_kernel<<<NBLK + NBG, TPB, 0, stream>>>(row, col, counts, bsum,
                                                    E, NBLK, NBUCK,
                                                    bucketed, x, W1, h1b, N, NBG);
    sort_kernel<<<NBUCK, TPB, 0, stream>>>(bucketed, counts, bsum, E, NBLK, NBUCK,
                                           csr, offs, dinv, h1b, h1p, N);
    gather1_kernel<<<(N + 15) / 16, TPB, 0, stream>>>(csr, offs, h1p, dinv, b1, h2p, N);
    gather2f_kernel<<<(N + 63) / 64, TPB, 0, stream>>>(csr, offs, h2p, dinv,
                                                       W2, b2, batch, out, N);
}

// Round 10
// 329.829 us; speedup vs baseline: 1.7913x; 1.0048x over previous
//
#include <hip/hip_runtime.h>

// 2-layer GCN, CSR-gather, bf16 payloads, zero global atomics.
//   hist(512-node buckets) -> scan1/scan2 -> [scatter ∥ gemm, 1:1] -> sort
//   -> gather1 -> gather2f (gather + W2 matmul + pooled output, fused).
// Kept: 1:1 scatter/gemm interleave (R9), 512-node buckets, packed 1-int
// bucket entries, bf16 h1 (R10), scan3g folded into consumers (R10),
// final fused into gather2 (R10), sorted coalesced bucket writes (R12),
// scan-diff counts + shfl scan + LDS union (R13), uint4 gathers (R13),
// K-split coalesced gemm loads (R16), 2-node/thread gemm (R17/R20),
// predicated gather loads (R19), 32-edge gather rounds (R20).
// R18 history: global-atomic CSR REFUTED (random 4B stores, WRITE 208MB).
// R19 history: request-count cut NEUTRAL -> gathers latency-bound.
// R21: pairwise software-pipelined gathers.  gather1: each 16-lane group
//   owns 2 nodes; the paired round issues 4 csr loads + 8 predicated
//   uint4 feat loads back-to-back before any accumulate (in-flight depth
//   2x, exposed latency per node ~halved).  gather2f phase 1: the 4
//   per-group nodes become 2 pipelined pairs (8 serial latency hops -> 4).
//   deg>32 tails use the single-node round (rare).

#define TPB 256
#define CHUNK 4096          // edges per stage-1 block
#define BK_SHIFT 9
#define NPB 512             // nodes per bucket = 1 << BK_SHIFT
#define W1S 20              // w1s k-row stride in floats (bank-spread pad)

__device__ __forceinline__ float bf2f(unsigned short u) {
    union { unsigned int i; float f; } v; v.i = ((unsigned int)u) << 16; return v.f;
}
__device__ __forceinline__ unsigned short f2bf(float f) {
    union { float f; unsigned int i; } v; v.f = f;
    unsigned int r = v.i + 0x7fff + ((v.i >> 16) & 1);   // RNE
    return (unsigned short)(r >> 16);
}
// accumulate 8 bf16 (one uint4) into a[0..7]
__device__ __forceinline__ void bfacc8(uint4 v, float* a) {
    union { unsigned int i; float f; } lo, hi;
    lo.i = v.x << 16; hi.i = v.x & 0xffff0000u; a[0] += lo.f; a[1] += hi.f;
    lo.i = v.y << 16; hi.i = v.y & 0xffff0000u; a[2] += lo.f; a[3] += hi.f;
    lo.i = v.z << 16; hi.i = v.z & 0xffff0000u; a[4] += lo.f; a[5] += hi.f;
    lo.i = v.w << 16; hi.i = v.w & 0xffff0000u; a[6] += lo.f; a[7] += hi.f;
}
__device__ __forceinline__ void bfunp8(uint4 v, float* a) {
    union { unsigned int i; float f; } lo, hi;
    lo.i = v.x << 16; hi.i = v.x & 0xffff0000u; a[0] = lo.f; a[1] = hi.f;
    lo.i = v.y << 16; hi.i = v.y & 0xffff0000u; a[2] = lo.f; a[3] = hi.f;
    lo.i = v.z << 16; hi.i = v.z & 0xffff0000u; a[4] = lo.f; a[5] = hi.f;
    lo.i = v.w << 16; hi.i = v.w & 0xffff0000u; a[6] = lo.f; a[7] = hi.f;
}

// single-node 32-edge round (tail path), predicated uint4 loads (R19/R20)
__device__ __forceinline__ void gather32(const int* __restrict__ csr,
                                         const unsigned short* __restrict__ feat,
                                         int p, int p1, int l, int half, int sub,
                                         float* a) {
    int s_lo = csr[min(p + l, p1 - 1)];
    int s_hi = csr[min(p + 16 + l, p1 - 1)];
    int rem = p1 - p;
    int e0 = sub, e1 = 8 + sub, e2 = 16 + sub, e3 = 24 + sub;
    int src0 = __shfl(s_lo, e0, 16);
    int src1 = __shfl(s_lo, e1, 16);
    int src2 = __shfl(s_hi, e0, 16);
    int src3 = __shfl(s_hi, e1, 16);
    uint4 u0 = make_uint4(0, 0, 0, 0), u1 = make_uint4(0, 0, 0, 0);
    uint4 u2 = make_uint4(0, 0, 0, 0), u3 = make_uint4(0, 0, 0, 0);
    if (e0 < rem) u0 = *(const uint4*)&feat[(size_t)src0 * 16 + 8 * half];
    if (e1 < rem) u1 = *(const uint4*)&feat[(size_t)src1 * 16 + 8 * half];
    if (e2 < rem) u2 = *(const uint4*)&feat[(size_t)src2 * 16 + 8 * half];
    if (e3 < rem) u3 = *(const uint4*)&feat[(size_t)src3 * 16 + 8 * half];
    bfacc8(u0, a);
    bfacc8(u1, a);
    bfacc8(u2, a);
    bfacc8(u3, a);
}

// paired 32-edge round for two nodes: 4 csr loads + 8 predicated feat
// loads all issued before any accumulate (R21 in-flight depth 2x).
__device__ __forceinline__ void gather32_pair(const int* __restrict__ csr,
                                              const unsigned short* __restrict__ feat,
                                              int pA, int pA1, int pB, int pB1,
                                              int l, int half, int sub,
                                              float* a, float* b) {
    int sAlo = csr[min(pA + l, pA1 - 1)];
    int sAhi = csr[min(pA + 16 + l, pA1 - 1)];
    int sBlo = csr[min(pB + l, pB1 - 1)];
    int sBhi = csr[min(pB + 16 + l, pB1 - 1)];
    int remA = pA1 - pA, remB = pB1 - pB;
    int e0 = sub, e1 = 8 + sub, e2 = 16 + sub, e3 = 24 + sub;
    int sa0 = __shfl(sAlo, e0, 16), sa1 = __shfl(sAlo, e1, 16);
    int sa2 = __shfl(sAhi, e0, 16), sa3 = __shfl(sAhi, e1, 16);
    int sb0 = __shfl(sBlo, e0, 16), sb1 = __shfl(sBlo, e1, 16);
    int sb2 = __shfl(sBhi, e0, 16), sb3 = __shfl(sBhi, e1, 16);
    uint4 uA0 = make_uint4(0,0,0,0), uA1 = make_uint4(0,0,0,0);
    uint4 uA2 = make_uint4(0,0,0,0), uA3 = make_uint4(0,0,0,0);
    uint4 uB0 = make_uint4(0,0,0,0), uB1 = make_uint4(0,0,0,0);
    uint4 uB2 = make_uint4(0,0,0,0), uB3 = make_uint4(0,0,0,0);
    if (e0 < remA) uA0 = *(const uint4*)&feat[(size_t)sa0 * 16 + 8 * half];
    if (e1 < remA) uA1 = *(const uint4*)&feat[(size_t)sa1 * 16 + 8 * half];
    if (e2 < remA) uA2 = *(const uint4*)&feat[(size_t)sa2 * 16 + 8 * half];
    if (e3 < remA) uA3 = *(const uint4*)&feat[(size_t)sa3 * 16 + 8 * half];
    if (e0 < remB) uB0 = *(const uint4*)&feat[(size_t)sb0 * 16 + 8 * half];
    if (e1 < remB) uB1 = *(const uint4*)&feat[(size_t)sb1 * 16 + 8 * half];
    if (e2 < remB) uB2 = *(const uint4*)&feat[(size_t)sb2 * 16 + 8 * half];
    if (e3 < remB) uB3 = *(const uint4*)&feat[(size_t)sb3 * 16 + 8 * half];
    bfacc8(uA0, a); bfacc8(uA1, a); bfacc8(uA2, a); bfacc8(uA3, a);
    bfacc8(uB0, b); bfacc8(uB1, b); bfacc8(uB2, b); bfacc8(uB3, b);
}

// S1a: counts[bk*nblk + blk] = #edges in block blk with col>>9 == bk
__global__ __launch_bounds__(TPB) void hist_kernel(const int* __restrict__ col,
                                                   int* __restrict__ counts,
                                                   int E, int nblk, int nbuck) {
    __shared__ int hist[512];
    int t = threadIdx.x;
    for (int i = t; i < nbuck; i += TPB) hist[i] = 0;
    __syncthreads();
    int e0 = blockIdx.x * CHUNK;
    for (int i = t; i < CHUNK; i += TPB) {
        int e = e0 + i;
        if (e < E) atomicAdd(&hist[col[e] >> BK_SHIFT], 1);   // LDS atomic
    }
    __syncthreads();
    for (int i = t; i < nbuck; i += TPB) counts[i * nblk + blockIdx.x] = hist[i];
}

// scan1: per-256-block exclusive scan (counts in place), bsum[b]=block total
__global__ __launch_bounds__(TPB) void scan1_kernel(const int* __restrict__ in,
                                                    int* __restrict__ out,
                                                    int* __restrict__ bsum, int L) {
    __shared__ int s[TPB];
    int t = threadIdx.x;
    int i = blockIdx.x * TPB + t;
    int d = (i < L) ? in[i] : 0;
    s[t] = d; __syncthreads();
    for (int off = 1; off < TPB; off <<= 1) {
        int v = (t >= off) ? s[t - off] : 0;
        __syncthreads();
        s[t] += v;
        __syncthreads();
    }
    if (i < L) out[i] = s[t] - d;
    if (t == TPB - 1) bsum[blockIdx.x] = s[t];
}

// scan2: single-block exclusive scan of up to 2048 block sums (2 elems/thread)
__global__ __launch_bounds__(1024) void scan2_kernel(int* __restrict__ bsum, int nb) {
    __shared__ int s[1024];
    int t = threadIdx.x;
    int i0 = t * 2, i1 = t * 2 + 1;
    int v0 = (i0 < nb) ? bsum[i0] : 0;
    int v1 = (i1 < nb) ? bsum[i1] : 0;
    int pv = v0 + v1;
    s[t] = pv; __syncthreads();
    for (int off = 1; off < 1024; off <<= 1) {
        int u = (t >= off) ? s[t - off] : 0;
        __syncthreads();
        s[t] += u;
        __syncthreads();
    }
    int exc = s[t] - pv;
    if (i0 < nb) bsum[i0] = exc;
    if (i1 < nb) bsum[i1] = exc + v0;
}

// cbase[f] = counts[f] + bsum[f>>8]   (scan3g folded into consumers)
__device__ __forceinline__ int cbase_at(const int* counts, const int* bsum, int f) {
    return counts[f] + bsum[f >> 8];
}

// S1c ∥ gemm, block-interleaved 1:1.
// Scatter: counts from scan diffs, shfl-scan local offsets, LDS counting
//   sort, bucket-ordered coalesced writes.
// Gemm: 4 threads/node K-split, 2 nodes/thread (R17/R20).
__global__ __launch_bounds__(TPB) void s1c_gemm_kernel(
        const int* __restrict__ row, const int* __restrict__ col,
        const int* __restrict__ counts, const int* __restrict__ bsum,
        int E, int nblk, int nbuck,
        int* __restrict__ bucketed,
        const float* __restrict__ x, const float* __restrict__ W1,
        unsigned short* __restrict__ h1b, int N, int nbg) {
    // unioned LDS: scatter uses 12352 B, gemm uses 10240 B (w1s stride-20)
    __shared__ __align__(16) char sbuf[2048 + 2048 + 8192 + 64];
    int* slhist = (int*)sbuf;                               // 512 ints (cursor)
    int* sgd    = (int*)(sbuf + 2048);                      // 512 ints
    unsigned short* ssidx = (unsigned short*)(sbuf + 4096); // 4096 ushort
    int* swtot  = (int*)(sbuf + 4096 + 8192);               // 4 ints
    float* w1s  = (float*)sbuf;                             // gemm: 128x20 f32

    int b = (int)blockIdx.x, t = threadIdx.x;
    int M = min(nblk, nbg);
    int role, id;
    if (b < 2 * M) { role = b & 1; id = b >> 1; }
    else           { role = (nblk > nbg) ? 0 : 1; id = b - M; }

    if (role == 0) {                         // block-local counting sort
        int e0 = id * CHUNK;
        int nE = min(CHUNK, E - e0);
        int Ltot = nbuck * nblk;
        int lane = t & 63, w = t >> 6;
        int bk0 = 2 * t, bk1 = 2 * t + 1;
        // per-bin counts for this chunk from global-scan differences
        int cb0 = 0, cb1 = 0, c0 = 0, c1 = 0;
        if (bk0 < nbuck) {
            int f = bk0 * nblk + id;
            cb0 = cbase_at(counts, bsum, f);
            int nx = (f + 1 < Ltot) ? cbase_at(counts, bsum, f + 1) : E;
            c0 = nx - cb0;
        }
        if (bk1 < nbuck) {
            int f = bk1 * nblk + id;
            cb1 = cbase_at(counts, bsum, f);
            int nx = (f + 1 < Ltot) ? cbase_at(counts, bsum, f + 1) : E;
            c1 = nx - cb1;
        }
        int s = c0 + c1;
        // wave inclusive scan of s over 64 lanes (bin order == thread order)
        int v = s;
#pragma unroll
        for (int d = 1; d < 64; d <<= 1) {
            int u2 = __shfl_up(v, d, 64);
            if (lane >= d) v += u2;
        }
        if (lane == 63) swtot[w] = v;
        __syncthreads();
        int wbase = 0;
#pragma unroll
        for (int i = 0; i < 4; ++i) wbase += (i < w) ? swtot[i] : 0;
        int o0 = wbase + v - s;              // local exclusive start of bk0
        int o1 = o0 + c0;
        if (bk0 < nbuck) { slhist[bk0] = o0; sgd[bk0] = cb0 - o0; }
        if (bk1 < nbuck) { slhist[bk1] = o1; sgd[bk1] = cb1 - o1; }
        __syncthreads();
        // scatter chunk-local indices into sorted order
        for (int i = t; i < nE; i += TPB) {
            int c = col[e0 + i];
            int lp = atomicAdd(&slhist[c >> BK_SHIFT], 1);     // LDS atomic
            ssidx[lp] = (unsigned short)i;
        }
        __syncthreads();
        // write out in bucket order -> runs of consecutive addresses
        for (int j = t; j < nE; j += TPB) {
            int i = ssidx[j];
            int c = col[e0 + i];                               // L1/L2-hot
            int r = row[e0 + i];
            bucketed[sgd[c >> BK_SHIFT] + j] = ((c & (NPB - 1)) << 18) | r;
        }
        return;
    }
    // gemm: h1b[n] = bf16(x[n] @ W1).  4 threads/node K-split, 2 nodes/thread.
    for (int i = t; i < 128 * 16; i += TPB)
        w1s[(i >> 4) * W1S + (i & 15)] = W1[i];
    __syncthreads();
    int g = t >> 2, q = t & 3;
    int nA = id * 128 + g;
    int nB = nA + 64;
    int nAc = min(nA, N - 1), nBc = min(nB, N - 1);
    const float4* xA = (const float4*)(x + (size_t)nAc * 128);
    const float4* xB = (const float4*)(x + (size_t)nBc * 128);
    float4 xvA[8], xvB[8];
#pragma unroll
    for (int i = 0; i < 8; ++i) xvA[i] = xA[i * 4 + q];   // 16 loads in flight
#pragma unroll
    for (int i = 0; i < 8; ++i) xvB[i] = xB[i * 4 + q];
    float accA[16], accB[16];
#pragma unroll
    for (int k = 0; k < 16; ++k) { accA[k] = 0.f; accB[k] = 0.f; }
#pragma unroll
    for (int i = 0; i < 8; ++i) {
        float xjA[4] = {xvA[i].x, xvA[i].y, xvA[i].z, xvA[i].w};
        float xjB[4] = {xvB[i].x, xvB[i].y, xvB[i].z, xvB[i].w};
#pragma unroll
        for (int j = 0; j < 4; ++j) {
            int k = i * 16 + q * 4 + j;
            const float4* w4 = (const float4*)&w1s[k * W1S];
            float4 wa = w4[0], wb = w4[1], wc = w4[2], wd = w4[3];
            float xa = xjA[j], xb = xjB[j];
            accA[0]  = fmaf(xa, wa.x, accA[0]);  accA[1]  = fmaf(xa, wa.y, accA[1]);
            accA[2]  = fmaf(xa, wa.z, accA[2]);  accA[3]  = fmaf(xa, wa.w, accA[3]);
            accA[4]  = fmaf(xa, wb.x, accA[4]);  accA[5]  = fmaf(xa, wb.y, accA[5]);
            accA[6]  = fmaf(xa, wb.z, accA[6]);  accA[7]  = fmaf(xa, wb.w, accA[7]);
            accA[8]  = fmaf(xa, wc.x, accA[8]);  accA[9]  = fmaf(xa, wc.y, accA[9]);
            accA[10] = fmaf(xa, wc.z, accA[10]); accA[11] = fmaf(xa, wc.w, accA[11]);
            accA[12] = fmaf(xa, wd.x, accA[12]); accA[13] = fmaf(xa, wd.y, accA[13]);
            accA[14] = fmaf(xa, wd.z, accA[14]); accA[15] = fmaf(xa, wd.w, accA[15]);
            accB[0]  = fmaf(xb, wa.x, accB[0]);  accB[1]  = fmaf(xb, wa.y, accB[1]);
            accB[2]  = fmaf(xb, wa.z, accB[2]);  accB[3]  = fmaf(xb, wa.w, accB[3]);
            accB[4]  = fmaf(xb, wb.x, accB[4]);  accB[5]  = fmaf(xb, wb.y, accB[5]);
            accB[6]  = fmaf(xb, wb.z, accB[6]);  accB[7]  = fmaf(xb, wb.w, accB[7]);
            accB[8]  = fmaf(xb, wc.x, accB[8]);  accB[9]  = fmaf(xb, wc.y, accB[9]);
            accB[10] = fmaf(xb, wc.z, accB[10]); accB[11] = fmaf(xb, wc.w, accB[11]);
            accB[12] = fmaf(xb, wd.x, accB[12]); accB[13] = fmaf(xb, wd.y, accB[13]);
            accB[14] = fmaf(xb, wd.z, accB[14]); accB[15] = fmaf(xb, wd.w, accB[15]);
        }
    }
    // butterfly-reduce both accs across the 4 K-split lanes
#pragma unroll
    for (int d = 1; d < 4; d <<= 1) {
#pragma unroll
        for (int k = 0; k < 16; ++k) {
            accA[k] += __shfl_xor(accA[k], d, 4);
            accB[k] += __shfl_xor(accB[k], d, 4);
        }
    }
    if (nA < N) {                            // lane q stores feats 4q..4q+3
        unsigned int u0 = (unsigned int)f2bf(accA[4 * q]) |
                          ((unsigned int)f2bf(accA[4 * q + 1]) << 16);
        unsigned int u1 = (unsigned int)f2bf(accA[4 * q + 2]) |
                          ((unsigned int)f2bf(accA[4 * q + 3]) << 16);
        *(uint2*)&h1b[(size_t)nA * 16 + 4 * q] = make_uint2(u0, u1);
    }
    if (nB < N) {
        unsigned int u0 = (unsigned int)f2bf(accB[4 * q]) |
                          ((unsigned int)f2bf(accB[4 * q + 1]) << 16);
        unsigned int u1 = (unsigned int)f2bf(accB[4 * q + 2]) |
                          ((unsigned int)f2bf(accB[4 * q + 3]) << 16);
        *(uint2*)&h1b[(size_t)nB * 16 + 4 * q] = make_uint2(u0, u1);
    }
}

// S2: one block per 512-node bucket: counting sort, emit csr/offs/dinv,
// h1p = bf16(dinv * h1b).
__global__ __launch_bounds__(TPB) void sort_kernel(
        const int* __restrict__ bucketed,
        const int* __restrict__ counts, const int* __restrict__ bsum,
        int E, int nblk, int nbuck,
        int* __restrict__ csr, int* __restrict__ offs, float* __restrict__ dinv,
        const unsigned short* __restrict__ h1b, unsigned short* __restrict__ h1p, int N) {
    __shared__ int lhist[NPB];
    __shared__ int part[TPB];
    __shared__ float sdinv[NPB];
    int bk = blockIdx.x, t = threadIdx.x;
    int n0 = bk << BK_SHIFT;
    int n1 = min(n0 + NPB, N);
    int e0 = cbase_at(counts, bsum, bk * nblk);
    int e1 = (bk + 1 < nbuck) ? cbase_at(counts, bsum, (bk + 1) * nblk) : E;

    lhist[t] = 0; lhist[t + TPB] = 0;
    __syncthreads();
    for (int i = e0 + t; i < e1; i += TPB)
        atomicAdd(&lhist[bucketed[i] >> 18], 1);               // LDS atomic
    __syncthreads();

    int base = t * 2;
    int c0 = lhist[base], c1 = lhist[base + 1];
    int s = c0 + c1;
    part[t] = s;
    __syncthreads();
    for (int off = 1; off < TPB; off <<= 1) {
        int v = (t >= off) ? part[t - off] : 0;
        __syncthreads();
        part[t] += v;
        __syncthreads();
    }
    int o0 = e0 + part[t] - s;
    int o1 = o0 + c0;
    lhist[base] = o0; lhist[base + 1] = o1;
    sdinv[base]     = rsqrtf((float)c0 + 1.0f);
    sdinv[base + 1] = rsqrtf((float)c1 + 1.0f);
    int n = n0 + base;
    if (n + 0 < N) { offs[n + 0] = o0; dinv[n + 0] = sdinv[base]; }
    if (n + 1 < N) { offs[n + 1] = o1; dinv[n + 1] = sdinv[base + 1]; }
    __syncthreads();

    for (int i = e0 + t; i < e1; i += TPB) {
        int v = bucketed[i];
        int pos = atomicAdd(&lhist[v >> 18], 1);               // LDS atomic
        csr[pos] = v & 0x3FFFF;
    }
    int nq = (n1 - n0) * 4;                  // one quad (4 feats) per i
    for (int i = t; i < nq; i += TPB) {
        float dv = sdinv[i >> 2];
        uint2 u = ((const uint2*)h1b)[(size_t)n0 * 4 + i];
        float f0 = bf2f((unsigned short)(u.x & 0xffff));
        float f1 = bf2f((unsigned short)(u.x >> 16));
        float f2 = bf2f((unsigned short)(u.y & 0xffff));
        float f3 = bf2f((unsigned short)(u.y >> 16));
        ((ushort4*)h1p)[(size_t)n0 * 4 + i] =
            make_ushort4(f2bf(f0 * dv), f2bf(f1 * dv), f2bf(f2 * dv), f2bf(f3 * dv));
    }
    if (bk == 0 && t == 0) offs[N] = E;
}

// gather1: 16 lanes per 2 nodes (R21 pair-pipelined).  Paired 32-edge
// rounds issue 4 csr + 8 feat loads before any accumulate; rare deg>32
// tails use single-node rounds.  8-lane tree reduce; lanes 0/1 finalize.
// h2p[c] = bf16( dinv[c]*relu( dinv[c]*(sum h1p[src] + h1p[c]) + b1 ) )
__global__ __launch_bounds__(TPB) void gather1_kernel(const int* __restrict__ csr,
                                                      const int* __restrict__ offs,
                                                      const unsigned short* __restrict__ h1p,
                                                      const float* __restrict__ dinv,
                                                      const float* __restrict__ b1,
                                                      unsigned short* __restrict__ h2p, int N) {
    int t = threadIdx.x;
    int grp = t >> 4, l = t & 15;
    int half = l & 1;                        // which 8-feature half-row
    int sub  = l >> 1;                       // edge slot 0..7
    int cA = blockIdx.x * 32 + grp * 2;
    int cB = cA + 1;
    if (cA >= N) return;
    bool hasB = cB < N;
    int pA = offs[cA], pA1 = offs[cA + 1];
    int pB = hasB ? offs[cB] : 0;
    int pB1 = hasB ? offs[cB + 1] : 0;
    float a[8], bb[8];
#pragma unroll
    for (int k = 0; k < 8; ++k) { a[k] = 0.f; bb[k] = 0.f; }
    while (pA < pA1 && pB < pB1) {           // paired rounds (usually 1)
        gather32_pair(csr, h1p, pA, pA1, pB, pB1, l, half, sub, a, bb);
        pA += 32; pB += 32;
    }
    while (pA < pA1) { gather32(csr, h1p, pA, pA1, l, half, sub, a); pA += 32; }
    while (pB < pB1) { gather32(csr, h1p, pB, pB1, l, half, sub, bb); pB += 32; }
#pragma unroll
    for (int d = 2; d < 16; d <<= 1) {
#pragma unroll
        for (int k = 0; k < 8; ++k) {
            a[k]  += __shfl_xor(a[k], d, 16);
            bb[k] += __shfl_xor(bb[k], d, 16);
        }
    }
    if (l < 2) {                             // l==half here
#pragma unroll
        for (int side = 0; side < 2; ++side) {
            int c = side ? cB : cA;
            float* av = side ? bb : a;
            if (side && !hasB) break;
            float dc = dinv[c];
            uint4 sv = *(const uint4*)&h1p[(size_t)c * 16 + 8 * l];
            float sf[8];
            bfunp8(sv, sf);
            unsigned int uo[4];
#pragma unroll
            for (int q = 0; q < 4; ++q) {
                float r0 = fmaf(dc, av[2 * q] + sf[2 * q], b1[8 * l + 2 * q]);
                float r1 = fmaf(dc, av[2 * q + 1] + sf[2 * q + 1], b1[8 * l + 2 * q + 1]);
                r0 = dc * fmaxf(r0, 0.f);
                r1 = dc * fmaxf(r1, 0.f);
                uo[q] = (unsigned int)f2bf(r0) | ((unsigned int)f2bf(r1) << 16);
            }
            *(uint4*)&h2p[(size_t)c * 16 + 8 * l] = make_uint4(uo[0], uo[1], uo[2], uo[3]);
        }
    }
}

// gather2f: fused gather2 + W2 matmul + sorted-batch pooling.  Block = 64 nodes.
// Phase 1: 16 groups x 16 lanes gather a2 rows — 2 pipelined PAIRS per
// group (R21: 8 serial latency hops -> 4) into LDS asT.
// Phase 2: wave w: 64 lanes = output dims, 16 nodes from asT, W2 slice in regs,
//          run-accumulate; uniform-batch blocks pool in LDS, flush 64 atomics.
__global__ __launch_bounds__(TPB) void gather2f_kernel(
        const int* __restrict__ csr, const int* __restrict__ offs,
        const unsigned short* __restrict__ h2p, const float* __restrict__ dinv,
        const float* __restrict__ W2, const float* __restrict__ b2,
        const int* __restrict__ batch, float* __restrict__ out, int N) {
    __shared__ float w2s[16 * 64];
    __shared__ float asT[64 * 17];
    __shared__ float pool[64];
    int t = threadIdx.x;
    for (int i = t; i < 16 * 64; i += TPB) w2s[i] = W2[i];
    if (t < 64) pool[t] = 0.f;

    int n0 = blockIdx.x * 64;
    int nLast = min(n0 + 63, N - 1);
    int g0 = batch[n0];
    bool uniform = (batch[nLast] == g0);     // batch sorted

    // phase 1: gather, 2 pipelined pairs per group
    int grp = t >> 4, l = t & 15;
    int half = l & 1, sub = l >> 1;
#pragma unroll 1
    for (int itp = 0; itp < 2; ++itp) {
        int mA = grp * 4 + itp * 2;
        int mB = mA + 1;
        int cA = n0 + mA, cB = n0 + mB;
        if (cA < N) {
            bool hasB = cB < N;
            int pA = offs[cA], pA1 = offs[cA + 1];
            int pB = hasB ? offs[cB] : 0;
            int pB1 = hasB ? offs[cB + 1] : 0;
            float a[8], bb[8];
#pragma unroll
            for (int k = 0; k < 8; ++k) { a[k] = 0.f; bb[k] = 0.f; }
            while (pA < pA1 && pB < pB1) {
                gather32_pair(csr, h2p, pA, pA1, pB, pB1, l, half, sub, a, bb);
                pA += 32; pB += 32;
            }
            while (pA < pA1) { gather32(csr, h2p, pA, pA1, l, half, sub, a); pA += 32; }
            while (pB < pB1) { gather32(csr, h2p, pB, pB1, l, half, sub, bb); pB += 32; }
#pragma unroll
            for (int d = 2; d < 16; d <<= 1) {
#pragma unroll
                for (int k = 0; k < 8; ++k) {
                    a[k]  += __shfl_xor(a[k], d, 16);
                    bb[k] += __shfl_xor(bb[k], d, 16);
                }
            }
            if (l < 2) {
#pragma unroll
                for (int side = 0; side < 2; ++side) {
                    int c = side ? cB : cA;
                    int m = side ? mB : mA;
                    float* av = side ? bb : a;
                    if (side && !hasB) break;
                    float dc = dinv[c];
                    uint4 sv = *(const uint4*)&h2p[(size_t)c * 16 + 8 * l];
                    float sf[8];
                    bfunp8(sv, sf);
#pragma unroll
                    for (int k = 0; k < 8; ++k)
                        asT[m * 17 + 8 * l + k] = dc * (av[k] + sf[k]);
                }
            }
        }
    }
    __syncthreads();

    // phase 2: wave w covers nodes n0+16w .. n0+16w+15
    int wave = t >> 6, j = t & 63;
    float w2reg[16];
#pragma unroll
    for (int kx = 0; kx < 16; ++kx) w2reg[kx] = w2s[kx * 64 + j];
    float b2j = b2[j];
    float val = 0.f;
    int g_cur = -1;
#pragma unroll 1
    for (int mi = 0; mi < 16; ++mi) {
        int m = wave * 16 + mi;
        int c = n0 + m;
        if (c >= N) break;
        const float* ar = &asT[m * 17];
        float y = b2j;
#pragma unroll
        for (int kx = 0; kx < 16; ++kx) y = fmaf(ar[kx], w2reg[kx], y);
        if (uniform) {
            val += y;
        } else {
            int g = batch[c];
            if (g != g_cur) {
                if (g_cur >= 0) atomicAdd(&out[(size_t)g_cur * 64 + j], val);
                val = 0.f;
                g_cur = g;
            }
            val += y;
        }
    }
    if (uniform) {
        atomicAdd(&pool[j], val);            // LDS, 4-way per address
        __syncthreads();
        if (t < 64) atomicAdd(&out[(size_t)g0 * 64 + t], pool[t]);
    } else {
        if (g_cur >= 0) atomicAdd(&out[(size_t)g_cur * 64 + j], val);
    }
}

static inline size_t align64(size_t v) { return (v + 63) & ~(size_t)63; }

extern "C" void kernel_launch(void* const* d_in, const int* in_sizes, int n_in,
                              void* d_out, int out_size, void* d_ws, size_t ws_size,
                              hipStream_t stream) {
    const float* x     = (const float*)d_in[0];
    const int*   ei    = (const int*)d_in[1];
    const int*   batch = (const int*)d_in[2];
    const float* W1    = (const float*)d_in[3];
    const float* b1    = (const float*)d_in[4];
    const float* W2    = (const float*)d_in[5];
    const float* b2    = (const float*)d_in[6];

    const int N = in_sizes[0] / 128;
    const int E = in_sizes[1] / 2;
    const int* row = ei;        // edge_index[0]
    const int* col = ei + E;    // edge_index[1]

    const int NBLK  = (E + CHUNK - 1) / CHUNK;       // 782
    const int NBUCK = (N + NPB - 1) / NPB;           // 391 (<=512)
    const int L     = NBUCK * NBLK;                  // 305762
    const int NBS   = (L + TPB - 1) / TPB;           // 1195 (<=2048 for scan2)
    const int NBG   = (N + 127) / 128;               // 1563 gemm blocks

    char* p = (char*)d_ws;
    int*            counts   = (int*)p;            p += align64((size_t)L * 4);
    int*            bsum     = (int*)p;            p += align64(2048 * 4);
    int*            bucketed = (int*)p;            p += align64((size_t)E * 4);
    int*            csr      = (int*)p;            p += align64((size_t)E * 4);
    int*            offs     = (int*)p;            p += align64((size_t)(N + 1) * 4);
    float*          dinv     = (float*)p;          p += align64((size_t)N * 4);
    unsigned short* h1b      = (unsigned short*)p; p += align64((size_t)N * 16 * 2);
    unsigned short* h1p      = (unsigned short*)p; p += align64((size_t)N * 16 * 2);
    unsigned short* h2p      = (unsigned short*)p; p += align64((size_t)N * 16 * 2);
    float*          out      = (float*)d_out;

    hipMemsetAsync(out, 0, (size_t)out_size * sizeof(float), stream);

    hist_kernel<<<NBLK, TPB, 0, stream>>>(col, counts, E, NBLK, NBUCK);
    scan1_kernel<<<NBS, TPB, 0, stream>>>(counts, counts, bsum, L);
    scan2_kernel<<<1, 1024, 0, stream>>>(bsum, NBS);
    s1c_gemm_kernel<<<NBLK + NBG, TPB, 0, stream>>>(row, col, counts, bsum,
                                                    E, NBLK, NBUCK,
                                                    bucketed, x, W1, h1b, N, NBG);
    sort_kernel<<<NBUCK, TPB, 0, stream>>>(bucketed, counts, bsum, E, NBLK, NBUCK,
                                           csr, offs, dinv, h1b, h1p, N);
    gather1_kernel<<<(N + 31) / 32, TPB, 0, stream>>>(csr, offs, h1p, dinv, b1, h2p, N);
    gather2f_kernel<<<(N + 63) / 64, TPB, 0, stream>>>(csr, offs, h2p, dinv,
                                                       W2, b2, batch, out, N);
}